// Round 3
// baseline (3015.485 us; speedup 1.0000x reference)
//
#include <hip/hip_runtime.h>

// ---------------------------------------------------------------------------
// 2-layer GraphSAGE (mean aggregation), fp32.
//   h   = relu( mean_agg(x) @ W1l^T + b1 + x @ W1r^T )          [M,256]
//   p   = h @ W2l^T                                              [M,128]  (stored in d_out)
//   out = mean_agg(p) + b2 + h @ W2r^T                           [M,128]
// (mean_agg commutes with the right-multiply, halving layer-2 scatter width)
// Workspace layout (floats), total ~77.0 MB for M=50000:
//   deg[Mpad] | agg[M*128] (agg1, re-zeroed, reused as agg2p) | h[M*256]
// p is staged in d_out (dead before the final GEMM overwrites it).
// ---------------------------------------------------------------------------

__global__ void deg_kernel(const int* __restrict__ dst, float* __restrict__ deg, int E) {
    for (long i = (long)blockIdx.x * blockDim.x + threadIdx.x; i < E;
         i += (long)gridDim.x * blockDim.x) {
        atomicAdd(&deg[dst[i]], 1.0f);
    }
}

__global__ void invdeg_kernel(float* __restrict__ deg, int n) {
    int i = blockIdx.x * blockDim.x + threadIdx.x;
    if (i < n) deg[i] = 1.0f / fmaxf(deg[i], 1.0f);
}

// scatter-add feat[src[e]] into agg[dst[e]], F floats per row, float4 per thread
template<int F>
__global__ void scatter_kernel(const float* __restrict__ feat,
                               const int* __restrict__ src,
                               const int* __restrict__ dst,
                               float* __restrict__ agg, int E) {
    constexpr int F4  = F / 4;        // quads per row
    constexpr int EPB = 256 / F4;     // edges per block pass
    const int q    = (threadIdx.x & (F4 - 1)) * 4;
    const int slot = threadIdx.x / F4;
    for (long e = (long)blockIdx.x * EPB + slot; e < E; e += (long)gridDim.x * EPB) {
        const int s = src[e];
        const int d = dst[e];
        const float4 v = *reinterpret_cast<const float4*>(&feat[(long)s * F + q]);
        float* o = &agg[(long)d * F + q];
        atomicAdd(o + 0, v.x);
        atomicAdd(o + 1, v.y);
        atomicAdd(o + 2, v.z);
        atomicAdd(o + 3, v.w);
    }
}

// ---------------------------------------------------------------------------
// Tiled fp32 GEMM: C[M][NOUT] = (optional relu)(
//     [ph0: (A1 .* invdeg_row) @ B1^T] + A2 @ B2^T + [bias] + [Epi .* invdeg] )
// A*: [M][K] row-major, B*: [NOUT][K] row-major (i.e. C = A·B^T).
// ---------------------------------------------------------------------------
static constexpr int BM = 64, BN = 64, BK = 16;

template<int NOUT, int K, bool RELU, bool SCALED_PHASE, bool HAS_BIAS, bool EPI_ADD>
__global__ __launch_bounds__(256)
void sage_gemm(const float* __restrict__ A1, const float* __restrict__ B1,
               const float* __restrict__ A2, const float* __restrict__ B2,
               const float* __restrict__ invdeg, const float* __restrict__ bias,
               const float* __restrict__ Epi, float* __restrict__ C, int M)
{
    __shared__ float As[BK][BM + 4];
    __shared__ float Bs[BK][BN + 4];
    const int row0 = blockIdx.x * BM;
    const int col0 = blockIdx.y * BN;
    const int tid  = threadIdx.x;
    const int tx = tid & 15, ty = tid >> 4;
    const int lrow = tid >> 2;        // 0..63 (tile row / col being staged)
    const int lk4  = (tid & 3) * 4;   // k offset 0,4,8,12

    float acc[4][4] = {};

    for (int ph = SCALED_PHASE ? 0 : 1; ph < 2; ++ph) {
        const float* __restrict__ A = (ph == 0) ? A1 : A2;
        const float* __restrict__ B = (ph == 0) ? B1 : B2;
        for (int k0 = 0; k0 < K; k0 += BK) {
            // stage A tile (transposed into LDS)
            {
                const int gr = row0 + lrow;
                float4 v = make_float4(0.f, 0.f, 0.f, 0.f);
                if (gr < M) {
                    v = *reinterpret_cast<const float4*>(&A[(long)gr * K + k0 + lk4]);
                    if (SCALED_PHASE && ph == 0) {
                        const float s = invdeg[gr];
                        v.x *= s; v.y *= s; v.z *= s; v.w *= s;
                    }
                }
                As[lk4 + 0][lrow] = v.x;
                As[lk4 + 1][lrow] = v.y;
                As[lk4 + 2][lrow] = v.z;
                As[lk4 + 3][lrow] = v.w;
            }
            // stage B tile (transposed into LDS); NOUT % BN == 0 -> no guard
            {
                const int gc = col0 + lrow;
                const float4 v = *reinterpret_cast<const float4*>(&B[(long)gc * K + k0 + lk4]);
                Bs[lk4 + 0][lrow] = v.x;
                Bs[lk4 + 1][lrow] = v.y;
                Bs[lk4 + 2][lrow] = v.z;
                Bs[lk4 + 3][lrow] = v.w;
            }
            __syncthreads();
            #pragma unroll
            for (int kk = 0; kk < BK; ++kk) {
                const float4 a = *reinterpret_cast<const float4*>(&As[kk][ty * 4]);
                const float4 b = *reinterpret_cast<const float4*>(&Bs[kk][tx * 4]);
                const float av[4] = {a.x, a.y, a.z, a.w};
                const float bv[4] = {b.x, b.y, b.z, b.w};
                #pragma unroll
                for (int i = 0; i < 4; ++i)
                    #pragma unroll
                    for (int j = 0; j < 4; ++j)
                        acc[i][j] = fmaf(av[i], bv[j], acc[i][j]);
            }
            __syncthreads();
        }
    }

    // epilogue
    #pragma unroll
    for (int i = 0; i < 4; ++i) {
        const int r = row0 + ty * 4 + i;
        if (r < M) {
            const float s = EPI_ADD ? invdeg[r] : 0.f;
            #pragma unroll
            for (int j = 0; j < 4; ++j) {
                const int c = col0 + tx * 4 + j;
                float v = acc[i][j];
                if (HAS_BIAS) v += bias[c];
                if (EPI_ADD)  v += Epi[(long)r * NOUT + c] * s;
                if (RELU)     v = fmaxf(v, 0.f);
                C[(long)r * NOUT + c] = v;
            }
        }
    }
}

extern "C" void kernel_launch(void* const* d_in, const int* in_sizes, int n_in,
                              void* d_out, int out_size, void* d_ws, size_t ws_size,
                              hipStream_t stream) {
    const float* x   = (const float*)d_in[0];
    const int*   ei  = (const int*)d_in[1];
    const float* W1l = (const float*)d_in[2];
    const float* b1  = (const float*)d_in[3];
    const float* W1r = (const float*)d_in[4];
    const float* W2l = (const float*)d_in[5];
    const float* b2  = (const float*)d_in[6];
    const float* W2r = (const float*)d_in[7];
    float* out = (float*)d_out;

    const int M = in_sizes[0] / 128;   // 50000 nodes
    const int E = in_sizes[1] / 2;     // 800000 edges
    const int* src = ei;
    const int* dst = ei + E;

    float* ws = (float*)d_ws;
    const long Mpad = ((long)M + 255) / 256 * 256;
    float* deg = ws;                       // [Mpad]   (becomes invdeg)
    float* agg = deg + Mpad;               // [M*128]  agg1, later reused as agg2p
    float* h   = agg + (long)M * 128;      // [M*256]
    float* p   = out;                      // [M*128]  staged in d_out (dead before final GEMM)

    const size_t agg_bytes = (size_t)M * 128 * sizeof(float);

    // zero: deg + agg (contiguous prefix)
    hipMemsetAsync(d_ws, 0, (size_t)(Mpad + (long)M * 128) * sizeof(float), stream);

    const int TB = 256;
    // degrees
    deg_kernel<<<dim3((E + TB - 1) / TB), dim3(TB), 0, stream>>>(dst, deg, E);
    invdeg_kernel<<<dim3((M + TB - 1) / TB), dim3(TB), 0, stream>>>(deg, M);

    // layer-1 aggregation of x (128-wide)
    {
        int blocks = (int)(((long)E + 7) / 8);
        if (blocks > 25600) blocks = 25600;
        scatter_kernel<128><<<dim3(blocks), dim3(TB), 0, stream>>>(x, src, dst, agg, E);
    }

    // h = relu( (agg .* invdeg) @ W1l^T + x @ W1r^T + b1 )
    {
        dim3 grid((M + BM - 1) / BM, 256 / BN);
        sage_gemm<256, 128, true, true, true, false>
            <<<grid, dim3(TB), 0, stream>>>(agg, W1l, x, W1r, deg, b1, nullptr, h, M);
    }

    // p = h @ W2l^T   (p lives in d_out)
    {
        dim3 grid((M + BM - 1) / BM, 128 / BN);
        sage_gemm<128, 256, false, false, false, false>
            <<<grid, dim3(TB), 0, stream>>>(nullptr, nullptr, h, W2l, nullptr, nullptr, nullptr, p, M);
    }

    // re-zero agg buffer, then layer-2 aggregation of p (128-wide)
    hipMemsetAsync(agg, 0, agg_bytes, stream);
    {
        int blocks = (int)(((long)E + 7) / 8);
        if (blocks > 25600) blocks = 25600;
        scatter_kernel<128><<<dim3(blocks), dim3(TB), 0, stream>>>(p, src, dst, agg, E);
    }

    // out = h @ W2r^T + b2 + agg .* invdeg   (overwrites p in d_out)
    {
        dim3 grid((M + BM - 1) / BM, 128 / BN);
        sage_gemm<128, 256, false, false, true, true>
            <<<grid, dim3(TB), 0, stream>>>(nullptr, nullptr, h, W2r, deg, b2, agg, out, M);
    }
}

// Round 4
// 525.863 us; speedup vs baseline: 5.7344x; 5.7344x over previous
//
#include <hip/hip_runtime.h>

// ---------------------------------------------------------------------------
// 2-layer GraphSAGE (mean aggregation), fp32, CSR-pull aggregation.
//   CSR build (once per launch): hist -> scan -> bucket (src_sorted by dst)
//   mean1 = mean_agg(x)                  [M,128]  (pull, no atomics)
//   h     = relu(mean1 @ W1l^T + b1 + x @ W1r^T)   [M,256]
//   p     = h @ W2l^T                    [M,128]  (staged in d_out)
//   mean2 = mean_agg(p)                  [M,128]
//   out   = mean2 + b2 + h @ W2r^T       [M,128]
// (mean_agg commutes with the right-multiply, halving layer-2 aggregation width)
// Workspace: hist[Mal] offs[Mal] src_sorted[E] | aggbuf[M*128] h[M*256] ~80.5MB
// ---------------------------------------------------------------------------

__global__ void hist_kernel(const int* __restrict__ dst, int* __restrict__ hist, int E) {
    for (long i = (long)blockIdx.x * blockDim.x + threadIdx.x; i < E;
         i += (long)gridDim.x * blockDim.x) {
        atomicAdd(&hist[dst[i]], 1);
    }
}

// single-workgroup exclusive scan of hist[0..M) -> offs[0..M]; zeroes hist (reused as cursor)
__global__ __launch_bounds__(1024)
void scan_kernel(int* __restrict__ hist, int* __restrict__ offs, int M) {
    __shared__ int wsum[16];
    __shared__ int s_carry;
    const int tid  = threadIdx.x;
    const int lane = tid & 63, wid = tid >> 6;
    if (tid == 0) s_carry = 0;
    __syncthreads();
    for (int base = 0; base < M; base += 1024) {
        const int idx = base + tid;
        const int v = (idx < M) ? hist[idx] : 0;
        int x = v;
        #pragma unroll
        for (int d = 1; d < 64; d <<= 1) {
            const int y = __shfl_up(x, d, 64);
            if (lane >= d) x += y;
        }
        if (lane == 63) wsum[wid] = x;
        __syncthreads();
        if (wid == 0) {
            int ws = (lane < 16) ? wsum[lane] : 0;
            #pragma unroll
            for (int d = 1; d < 16; d <<= 1) {
                const int y = __shfl_up(ws, d, 64);
                if (lane >= d) ws += y;
            }
            if (lane < 16) wsum[lane] = ws;   // inclusive over waves
        }
        __syncthreads();
        const int waveoff = (wid == 0) ? 0 : wsum[wid - 1];
        const int carry   = s_carry;
        if (idx < M) {
            offs[idx] = carry + waveoff + x - v;  // exclusive
            hist[idx] = 0;                         // becomes bucket cursor
        }
        const int tile_total = wsum[15];
        __syncthreads();
        if (tid == 0) s_carry = carry + tile_total;
        __syncthreads();
    }
    if (tid == 0) offs[M] = s_carry;
}

__global__ void bucket_kernel(const int* __restrict__ src, const int* __restrict__ dst,
                              const int* __restrict__ offs, int* __restrict__ cursor,
                              int* __restrict__ src_sorted, int E) {
    for (long i = (long)blockIdx.x * blockDim.x + threadIdx.x; i < E;
         i += (long)gridDim.x * blockDim.x) {
        const int d = dst[i];
        const int pos = offs[d] + atomicAdd(&cursor[d], 1);
        src_sorted[pos] = src[i];
    }
}

// pull-mean aggregation: one wave per node, lane owns float2 column pair
template<int F>
__global__ __launch_bounds__(256)
void agg_mean_kernel(const float* __restrict__ feat, const int* __restrict__ src_sorted,
                     const int* __restrict__ offs, float* __restrict__ out, int M) {
    const int node = blockIdx.x * 4 + (threadIdx.x >> 6);
    if (node >= M) return;
    const int lane  = threadIdx.x & 63;
    const int start = offs[node], end = offs[node + 1];
    const int c = lane * 2;
    float2 acc = make_float2(0.f, 0.f);
    for (int e0 = start; e0 < end; e0 += 64) {
        const int n = min(64, end - e0);
        const int sv = (e0 + lane < end) ? src_sorted[e0 + lane] : 0;
        for (int j = 0; j < n; ++j) {
            const int s = __shfl(sv, j, 64);
            const float2 v = *reinterpret_cast<const float2*>(&feat[(long)s * F + c]);
            acc.x += v.x; acc.y += v.y;
        }
    }
    const float inv = (end > start) ? 1.0f / (float)(end - start) : 0.f;
    acc.x *= inv; acc.y *= inv;
    *reinterpret_cast<float2*>(&out[(long)node * F + c]) = acc;
}

// ---------------------------------------------------------------------------
// Tiled fp32 GEMM: C = (relu)( [ph0: A1@B1^T] + A2@B2^T + [bias] + [Epi] )
// A*: [M][K] row-major, B*: [NOUT][K] row-major.
// ---------------------------------------------------------------------------
static constexpr int BM = 64, BN = 64, BK = 16;

template<int NOUT, int K, bool RELU, bool TWO_PHASE, bool HAS_BIAS, bool EPI_ADD>
__global__ __launch_bounds__(256)
void sage_gemm(const float* __restrict__ A1, const float* __restrict__ B1,
               const float* __restrict__ A2, const float* __restrict__ B2,
               const float* __restrict__ bias, const float* __restrict__ Epi,
               float* __restrict__ C, int M)
{
    __shared__ float As[BK][BM + 4];
    __shared__ float Bs[BK][BN + 4];
    const int row0 = blockIdx.x * BM;
    const int col0 = blockIdx.y * BN;
    const int tid  = threadIdx.x;
    const int tx = tid & 15, ty = tid >> 4;
    const int lrow = tid >> 2;
    const int lk4  = (tid & 3) * 4;

    float acc[4][4] = {};

    for (int ph = TWO_PHASE ? 0 : 1; ph < 2; ++ph) {
        const float* __restrict__ A = (ph == 0) ? A1 : A2;
        const float* __restrict__ B = (ph == 0) ? B1 : B2;
        for (int k0 = 0; k0 < K; k0 += BK) {
            {
                const int gr = row0 + lrow;
                float4 v = make_float4(0.f, 0.f, 0.f, 0.f);
                if (gr < M) v = *reinterpret_cast<const float4*>(&A[(long)gr * K + k0 + lk4]);
                As[lk4 + 0][lrow] = v.x;
                As[lk4 + 1][lrow] = v.y;
                As[lk4 + 2][lrow] = v.z;
                As[lk4 + 3][lrow] = v.w;
            }
            {
                const int gc = col0 + lrow;
                const float4 v = *reinterpret_cast<const float4*>(&B[(long)gc * K + k0 + lk4]);
                Bs[lk4 + 0][lrow] = v.x;
                Bs[lk4 + 1][lrow] = v.y;
                Bs[lk4 + 2][lrow] = v.z;
                Bs[lk4 + 3][lrow] = v.w;
            }
            __syncthreads();
            #pragma unroll
            for (int kk = 0; kk < BK; ++kk) {
                const float4 a = *reinterpret_cast<const float4*>(&As[kk][ty * 4]);
                const float4 b = *reinterpret_cast<const float4*>(&Bs[kk][tx * 4]);
                const float av[4] = {a.x, a.y, a.z, a.w};
                const float bv[4] = {b.x, b.y, b.z, b.w};
                #pragma unroll
                for (int i = 0; i < 4; ++i)
                    #pragma unroll
                    for (int j = 0; j < 4; ++j)
                        acc[i][j] = fmaf(av[i], bv[j], acc[i][j]);
            }
            __syncthreads();
        }
    }

    #pragma unroll
    for (int i = 0; i < 4; ++i) {
        const int r = row0 + ty * 4 + i;
        if (r < M) {
            #pragma unroll
            for (int j = 0; j < 4; ++j) {
                const int c = col0 + tx * 4 + j;
                float v = acc[i][j];
                if (HAS_BIAS) v += bias[c];
                if (EPI_ADD)  v += Epi[(long)r * NOUT + c];
                if (RELU)     v = fmaxf(v, 0.f);
                C[(long)r * NOUT + c] = v;
            }
        }
    }
}

extern "C" void kernel_launch(void* const* d_in, const int* in_sizes, int n_in,
                              void* d_out, int out_size, void* d_ws, size_t ws_size,
                              hipStream_t stream) {
    const float* x   = (const float*)d_in[0];
    const int*   ei  = (const int*)d_in[1];
    const float* W1l = (const float*)d_in[2];
    const float* b1  = (const float*)d_in[3];
    const float* W1r = (const float*)d_in[4];
    const float* W2l = (const float*)d_in[5];
    const float* b2  = (const float*)d_in[6];
    const float* W2r = (const float*)d_in[7];
    float* out = (float*)d_out;

    const int M = in_sizes[0] / 128;   // 50000
    const int E = in_sizes[1] / 2;     // 800000
    const int* src = ei;
    const int* dst = ei + E;

    const int Mal = ((M + 64 + 63) / 64) * 64;   // >= M+1, 256B-aligned blocks
    int* hist       = (int*)d_ws;                 // [Mal] (cursor after scan)
    int* offs       = hist + Mal;                 // [Mal] (uses M+1)
    int* src_sorted = offs + Mal;                 // [E]
    float* aggbuf   = (float*)(src_sorted + ((E + 63) / 64) * 64);  // [M*128]
    float* h        = aggbuf + (long)M * 128;     // [M*256]
    float* p        = out;                        // [M*128] staged in d_out

    const int TB = 256;
    // --- CSR build (shared by both layers) ---
    hipMemsetAsync(hist, 0, (size_t)Mal * sizeof(int), stream);
    hist_kernel<<<dim3((E + TB - 1) / TB), dim3(TB), 0, stream>>>(dst, hist, E);
    scan_kernel<<<dim3(1), dim3(1024), 0, stream>>>(hist, offs, M);
    bucket_kernel<<<dim3((E + TB - 1) / TB), dim3(TB), 0, stream>>>(src, dst, offs, hist, src_sorted, E);

    // --- layer 1 ---
    agg_mean_kernel<128><<<dim3((M + 3) / 4), dim3(TB), 0, stream>>>(x, src_sorted, offs, aggbuf, M);
    {
        dim3 grid((M + BM - 1) / BM, 256 / BN);
        sage_gemm<256, 128, true, true, true, false>
            <<<grid, dim3(TB), 0, stream>>>(aggbuf, W1l, x, W1r, b1, nullptr, h, M);
    }

    // --- layer 2 ---
    {
        dim3 grid((M + BM - 1) / BM, 128 / BN);
        sage_gemm<128, 256, false, false, false, false>
            <<<grid, dim3(TB), 0, stream>>>(nullptr, nullptr, h, W2l, nullptr, nullptr, p, M);
    }
    agg_mean_kernel<128><<<dim3((M + 3) / 4), dim3(TB), 0, stream>>>(p, src_sorted, offs, aggbuf, M);
    {
        dim3 grid((M + BM - 1) / BM, 128 / BN);
        sage_gemm<128, 256, false, false, true, true>
            <<<grid, dim3(TB), 0, stream>>>(nullptr, nullptr, h, W2r, b2, aggbuf, out, M);
    }
}

// Round 5
// 405.479 us; speedup vs baseline: 7.4369x; 1.2969x over previous
//
#include <hip/hip_runtime.h>

// ---------------------------------------------------------------------------
// 2-layer GraphSAGE (mean aggr), CSR-pull aggregation + bf16-MFMA GEMMs.
//   CSR build: hist -> scan -> bucket (src_sorted by dst)
//   wsplit: W* -> bf16 hi/lo pairs (weights split; kills B-rounding error)
//   mean1 = mean_agg(x)            -> bf16            [M,128]
//   h     = relu(mean1@W1l^T + b1 + x@W1r^T) -> bf16  [M,256]   (MFMA, fp32 acc)
//   p     = h@W2l^T                -> fp32 (d_out)    [M,128]   (MFMA)
//   mean2 = mean_agg(p)            -> fp32            [M,128]
//   out   = h@W2r^T + b2 + mean2   -> fp32            [M,128]   (MFMA)
// A-operands plain bf16 (RNE), B split hi/lo (2 MFMAs), fp32 accumulate.
// ws: hist|offs|src_sorted | aggbuf(fp32 25.6MB; mean1-bf16 aliases it)
//     | h_bf16 25.6MB | Wsplit 512KB   total ~55.3MB
// ---------------------------------------------------------------------------

typedef short bf16x8 __attribute__((ext_vector_type(8)));
typedef float f32x4  __attribute__((ext_vector_type(4)));

__device__ __forceinline__ unsigned f2bf(float f) {         // RNE fp32->bf16 bits
    unsigned u = __float_as_uint(f);
    return (u + 0x7FFFu + ((u >> 16) & 1u)) >> 16;
}
__device__ __forceinline__ unsigned pack2(float a, float b) {
    return f2bf(a) | (f2bf(b) << 16);
}

// ----------------------------- CSR build -----------------------------------
__global__ void hist_kernel(const int* __restrict__ dst, int* __restrict__ hist, int E) {
    for (long i = (long)blockIdx.x * blockDim.x + threadIdx.x; i < E;
         i += (long)gridDim.x * blockDim.x)
        atomicAdd(&hist[dst[i]], 1);
}

__global__ __launch_bounds__(1024)
void scan_kernel(int* __restrict__ hist, int* __restrict__ offs, int M) {
    __shared__ int wsum[16];
    __shared__ int s_carry;
    const int tid = threadIdx.x;
    const int lane = tid & 63, wid = tid >> 6;
    if (tid == 0) s_carry = 0;
    __syncthreads();
    for (int base = 0; base < M; base += 1024) {
        const int idx = base + tid;
        const int v = (idx < M) ? hist[idx] : 0;
        int x = v;
        #pragma unroll
        for (int d = 1; d < 64; d <<= 1) {
            const int y = __shfl_up(x, d, 64);
            if (lane >= d) x += y;
        }
        if (lane == 63) wsum[wid] = x;
        __syncthreads();
        if (wid == 0) {
            int ws = (lane < 16) ? wsum[lane] : 0;
            #pragma unroll
            for (int d = 1; d < 16; d <<= 1) {
                const int y = __shfl_up(ws, d, 64);
                if (lane >= d) ws += y;
            }
            if (lane < 16) wsum[lane] = ws;
        }
        __syncthreads();
        const int waveoff = (wid == 0) ? 0 : wsum[wid - 1];
        const int carry = s_carry;
        if (idx < M) {
            offs[idx] = carry + waveoff + x - v;
            hist[idx] = 0;                       // becomes bucket cursor
        }
        const int tile_total = wsum[15];
        __syncthreads();
        if (tid == 0) s_carry = carry + tile_total;
        __syncthreads();
    }
    if (tid == 0) offs[M] = s_carry;
}

__global__ void bucket_kernel(const int* __restrict__ src, const int* __restrict__ dst,
                              const int* __restrict__ offs, int* __restrict__ cursor,
                              int* __restrict__ src_sorted, int E) {
    for (long i = (long)blockIdx.x * blockDim.x + threadIdx.x; i < E;
         i += (long)gridDim.x * blockDim.x) {
        const int d = dst[i];
        const int pos = offs[d] + atomicAdd(&cursor[d], 1);
        src_sorted[pos] = src[i];
    }
}

// ----------------------------- aggregation ---------------------------------
template<int F, bool BF16_OUT>
__global__ __launch_bounds__(256)
void agg_mean_kernel(const float* __restrict__ feat, const int* __restrict__ src_sorted,
                     const int* __restrict__ offs, void* __restrict__ outv, int M) {
    const int node = blockIdx.x * 4 + (threadIdx.x >> 6);
    if (node >= M) return;
    const int lane = threadIdx.x & 63;
    const int start = offs[node], end = offs[node + 1];
    const int c = lane * 2;
    float2 acc = make_float2(0.f, 0.f);
    for (int e0 = start; e0 < end; e0 += 64) {
        const int n = min(64, end - e0);
        const int sv = (e0 + lane < end) ? src_sorted[e0 + lane] : 0;
        for (int j = 0; j < n; ++j) {
            const int s = __shfl(sv, j, 64);
            const float2 v = *reinterpret_cast<const float2*>(&feat[(long)s * F + c]);
            acc.x += v.x; acc.y += v.y;
        }
    }
    const float inv = (end > start) ? 1.0f / (float)(end - start) : 0.f;
    acc.x *= inv; acc.y *= inv;
    if (BF16_OUT)
        ((unsigned*)outv)[(long)node * (F / 2) + lane] = pack2(acc.x, acc.y);
    else
        *reinterpret_cast<float2*>((float*)outv + (long)node * F + c) = acc;
}

// ----------------------------- weight split --------------------------------
__global__ void wsplit_kernel(const float* __restrict__ W, short* __restrict__ hi,
                              short* __restrict__ lo, int n) {
    const int i = blockIdx.x * 256 + threadIdx.x;
    if (i >= n) return;
    const float v = W[i];
    const unsigned h = f2bf(v);
    const float hf = __uint_as_float(h << 16);
    hi[i] = (short)h;
    lo[i] = (short)f2bf(v - hf);
}

// ----------------------------- MFMA GEMM -----------------------------------
// C[M][NOUT] tile 128x128, 4 waves (2x2), 16x16x32 bf16 MFMA, fp32 acc.
// A: [M][KP] (bf16 shorts if ABF, else fp32 converted on stage)
// W(hi/lo): [NOUT][KP] shorts.  Products: a*b_hi + a*b_lo.

template<int KP, bool ABF>
__device__ __forceinline__ void gemm_phase(const void* __restrict__ A,
    const short* __restrict__ Whi, const short* __restrict__ Wlo,
    int M, int row0, int col0,
    short (*As)[40], short (*Bh)[40], short (*Bl)[40], f32x4 (&acc)[4][4])
{
    const int tid = threadIdx.x;
    const int lane = tid & 63;
    const int wr = (tid >> 7) & 1, wc = (tid >> 6) & 1;
    const int l15 = lane & 15, l4 = lane >> 4;
    const int sr = tid >> 1;          // staged row 0..127
    const int sk = (tid & 1) * 16;    // k offset 0/16
    const int gr = row0 + sr;

    for (int k0 = 0; k0 < KP; k0 += 32) {
        if constexpr (ABF) {
            const short* ap = (const short*)A + (long)gr * KP + k0 + sk;
            uint4 v0 = make_uint4(0, 0, 0, 0), v1 = make_uint4(0, 0, 0, 0);
            if (gr < M) { v0 = *(const uint4*)ap; v1 = *(const uint4*)(ap + 8); }
            *(uint4*)&As[sr][sk]     = v0;
            *(uint4*)&As[sr][sk + 8] = v1;
        } else {
            const float* ap = (const float*)A + (long)gr * KP + k0 + sk;
            float4 f0, f1, f2, f3;
            f0 = f1 = f2 = f3 = make_float4(0.f, 0.f, 0.f, 0.f);
            if (gr < M) {
                f0 = *(const float4*)ap;       f1 = *(const float4*)(ap + 4);
                f2 = *(const float4*)(ap + 8); f3 = *(const float4*)(ap + 12);
            }
            *(uint4*)&As[sr][sk]     = make_uint4(pack2(f0.x, f0.y), pack2(f0.z, f0.w),
                                                  pack2(f1.x, f1.y), pack2(f1.z, f1.w));
            *(uint4*)&As[sr][sk + 8] = make_uint4(pack2(f2.x, f2.y), pack2(f2.z, f2.w),
                                                  pack2(f3.x, f3.y), pack2(f3.z, f3.w));
        }
        {
            const short* bh = Whi + (long)(col0 + sr) * KP + k0 + sk;
            const short* bl = Wlo + (long)(col0 + sr) * KP + k0 + sk;
            *(uint4*)&Bh[sr][sk]     = *(const uint4*)bh;
            *(uint4*)&Bh[sr][sk + 8] = *(const uint4*)(bh + 8);
            *(uint4*)&Bl[sr][sk]     = *(const uint4*)bl;
            *(uint4*)&Bl[sr][sk + 8] = *(const uint4*)(bl + 8);
        }
        __syncthreads();
        bf16x8 bhf[4], blf[4];
        #pragma unroll
        for (int n = 0; n < 4; ++n) {
            const int br = wc * 64 + n * 16 + l15;
            bhf[n] = *(const bf16x8*)&Bh[br][l4 * 8];
            blf[n] = *(const bf16x8*)&Bl[br][l4 * 8];
        }
        #pragma unroll
        for (int m = 0; m < 4; ++m) {
            const bf16x8 af = *(const bf16x8*)&As[wr * 64 + m * 16 + l15][l4 * 8];
            #pragma unroll
            for (int n = 0; n < 4; ++n) {
                acc[m][n] = __builtin_amdgcn_mfma_f32_16x16x32_bf16(af, bhf[n], acc[m][n], 0, 0, 0);
                acc[m][n] = __builtin_amdgcn_mfma_f32_16x16x32_bf16(af, blf[n], acc[m][n], 0, 0, 0);
            }
        }
        __syncthreads();
    }
}

template<int K1, int K2, int NOUT, bool TWO_PHASE, bool A1BF, bool A2BF,
         bool RELU, bool HAS_BIAS, bool EPI_ADD, bool OUT_BF16>
__global__ __launch_bounds__(256)
void mfma_gemm(const void* __restrict__ A1, const void* __restrict__ A2,
               const short* __restrict__ B1hi, const short* __restrict__ B1lo,
               const short* __restrict__ B2hi, const short* __restrict__ B2lo,
               const float* __restrict__ bias, const float* __restrict__ Epi,
               void* __restrict__ Cv, int M)
{
    __shared__ __align__(16) short As[128][40];
    __shared__ __align__(16) short Bh[128][40];
    __shared__ __align__(16) short Bl[128][40];
    const int row0 = blockIdx.x * 128, col0 = blockIdx.y * 128;
    f32x4 acc[4][4] = {};

    if constexpr (TWO_PHASE)
        gemm_phase<K1, A1BF>(A1, B1hi, B1lo, M, row0, col0, As, Bh, Bl, acc);
    gemm_phase<K2, A2BF>(A2, B2hi, B2lo, M, row0, col0, As, Bh, Bl, acc);

    const int tid = threadIdx.x, lane = tid & 63;
    const int wr = (tid >> 7) & 1, wc = (tid >> 6) & 1;
    const int l15 = lane & 15, l4 = lane >> 4;
    float bv[4];
    #pragma unroll
    for (int n = 0; n < 4; ++n)
        bv[n] = HAS_BIAS ? bias[col0 + wc * 64 + n * 16 + l15] : 0.f;
    #pragma unroll
    for (int m = 0; m < 4; ++m) {
        #pragma unroll
        for (int i = 0; i < 4; ++i) {
            const int r = row0 + wr * 64 + m * 16 + l4 * 4 + i;
            if (r < M) {
                #pragma unroll
                for (int n = 0; n < 4; ++n) {
                    const int c = col0 + wc * 64 + n * 16 + l15;
                    float v = acc[m][n][i] + bv[n];
                    if (EPI_ADD) v += Epi[(long)r * NOUT + c];
                    if (RELU)    v = fmaxf(v, 0.f);
                    if (OUT_BF16) ((short*)Cv)[(long)r * NOUT + c] = (short)f2bf(v);
                    else          ((float*)Cv)[(long)r * NOUT + c] = v;
                }
            }
        }
    }
}

// ----------------------------- launch --------------------------------------
extern "C" void kernel_launch(void* const* d_in, const int* in_sizes, int n_in,
                              void* d_out, int out_size, void* d_ws, size_t ws_size,
                              hipStream_t stream) {
    const float* x   = (const float*)d_in[0];
    const int*   ei  = (const int*)d_in[1];
    const float* W1l = (const float*)d_in[2];
    const float* b1  = (const float*)d_in[3];
    const float* W1r = (const float*)d_in[4];
    const float* W2l = (const float*)d_in[5];
    const float* b2  = (const float*)d_in[6];
    const float* W2r = (const float*)d_in[7];
    float* out = (float*)d_out;

    const int M = in_sizes[0] / 128;   // 50000
    const int E = in_sizes[1] / 2;     // 800000
    const int* src = ei;
    const int* dst = ei + E;

    const int Mal = ((M + 64 + 63) / 64) * 64;
    int* hist       = (int*)d_ws;                               // [Mal]
    int* offs       = hist + Mal;                               // [Mal]
    int* src_sorted = offs + Mal;                               // [E]
    float* aggbuf   = (float*)(src_sorted + ((E + 63) / 64) * 64); // [M*128] fp32 (mean2)
    short* mean1_bf = (short*)aggbuf;                           // [M*128] bf16 (aliases aggbuf)
    short* h_bf     = (short*)(aggbuf + (long)M * 128);         // [M*256] bf16
    short* wbuf     = (short*)(h_bf + (long)M * 256);           // 8 x 32768 shorts
    const int WN = 256 * 128;
    short *W1l_hi = wbuf,          *W1l_lo = wbuf + WN;
    short *W1r_hi = wbuf + 2 * WN, *W1r_lo = wbuf + 3 * WN;
    short *W2l_hi = wbuf + 4 * WN, *W2l_lo = wbuf + 5 * WN;
    short *W2r_hi = wbuf + 6 * WN, *W2r_lo = wbuf + 7 * WN;
    float* p = out;                                             // staged in d_out

    const int TB = 256;
    // CSR build
    hipMemsetAsync(hist, 0, (size_t)Mal * sizeof(int), stream);
    hist_kernel<<<dim3((E + TB - 1) / TB), dim3(TB), 0, stream>>>(dst, hist, E);
    scan_kernel<<<dim3(1), dim3(1024), 0, stream>>>(hist, offs, M);
    bucket_kernel<<<dim3((E + TB - 1) / TB), dim3(TB), 0, stream>>>(src, dst, offs, hist, src_sorted, E);

    // weight hi/lo split
    const int wgrid = (WN + TB - 1) / TB;
    wsplit_kernel<<<dim3(wgrid), dim3(TB), 0, stream>>>(W1l, W1l_hi, W1l_lo, WN);
    wsplit_kernel<<<dim3(wgrid), dim3(TB), 0, stream>>>(W1r, W1r_hi, W1r_lo, WN);
    wsplit_kernel<<<dim3(wgrid), dim3(TB), 0, stream>>>(W2l, W2l_hi, W2l_lo, WN);
    wsplit_kernel<<<dim3(wgrid), dim3(TB), 0, stream>>>(W2r, W2r_hi, W2r_lo, WN);

    const int MB = (M + 127) / 128;   // 391

    // layer 1
    agg_mean_kernel<128, true><<<dim3((M + 3) / 4), dim3(TB), 0, stream>>>(x, src_sorted, offs, mean1_bf, M);
    mfma_gemm<128, 128, 256, true, true, false, true, true, false, true>
        <<<dim3(MB, 2), dim3(TB), 0, stream>>>(mean1_bf, x, W1l_hi, W1l_lo, W1r_hi, W1r_lo,
                                               b1, nullptr, h_bf, M);
    // layer 2
    mfma_gemm<128, 256, 128, false, false, true, false, false, false, false>
        <<<dim3(MB, 1), dim3(TB), 0, stream>>>(nullptr, h_bf, nullptr, nullptr, W2l_hi, W2l_lo,
                                               nullptr, nullptr, p, M);
    agg_mean_kernel<128, false><<<dim3((M + 3) / 4), dim3(TB), 0, stream>>>(p, src_sorted, offs, aggbuf, M);
    mfma_gemm<128, 256, 128, false, false, true, false, true, true, false>
        <<<dim3(MB, 1), dim3(TB), 0, stream>>>(nullptr, h_bf, nullptr, nullptr, W2r_hi, W2r_lo,
                                               b2, aggbuf, out, M);
}

// Round 6
// 352.606 us; speedup vs baseline: 8.5520x; 1.1499x over previous
//
#include <hip/hip_runtime.h>

// ---------------------------------------------------------------------------
// 2-layer GraphSAGE (mean aggr), CSR-pull aggregation + bf16-MFMA GEMMs.
//   CSR build: hist -> scan -> bucket (src_sorted by dst)
//   x_bf = bf16(x); weights split hi/lo bf16 (2 MFMAs kill B-rounding)
//   mean1 = mean_agg(x_bf)                   -> bf16   [M,128]
//   h     = relu(mean1@W1l^T + b1 + x_bf@W1r^T) -> bf16 [M,256]  (MFMA, fp32 acc)
//   p     = h@W2l^T                          -> bf16 (in d_out)  (MFMA)
//   mean2 = mean_agg(p)                      -> fp32   [M,128]
//   out   = h@W2r^T + b2 + mean2             -> fp32   [M,128]   (MFMA)
// Aggregation gathers bf16 rows (256B) with 4x-unrolled loads, fp32 accum.
// ws: hist|offs|src_sorted | aggbuf fp32 25.6MB (mean1_bf aliases)
//     | h_bf 25.6MB | wbuf 0.5MB | x_bf 12.8MB   total ~68.1MB
// ---------------------------------------------------------------------------

typedef short bf16x8 __attribute__((ext_vector_type(8)));
typedef float f32x4  __attribute__((ext_vector_type(4)));

__device__ __forceinline__ unsigned f2bf(float f) {         // RNE fp32->bf16 bits
    unsigned u = __float_as_uint(f);
    return (u + 0x7FFFu + ((u >> 16) & 1u)) >> 16;
}
__device__ __forceinline__ unsigned pack2(float a, float b) {
    return f2bf(a) | (f2bf(b) << 16);
}
__device__ __forceinline__ float2 bfunpack(unsigned u) {    // (low, high) bf16 -> fp32
    return make_float2(__uint_as_float(u << 16), __uint_as_float(u & 0xffff0000u));
}

// ----------------------------- CSR build -----------------------------------
__global__ void hist_kernel(const int* __restrict__ dst, int* __restrict__ hist, int E) {
    for (long i = (long)blockIdx.x * blockDim.x + threadIdx.x; i < E;
         i += (long)gridDim.x * blockDim.x)
        atomicAdd(&hist[dst[i]], 1);
}

__global__ __launch_bounds__(1024)
void scan_kernel(int* __restrict__ hist, int* __restrict__ offs, int M) {
    __shared__ int wsum[16];
    __shared__ int s_carry;
    const int tid = threadIdx.x;
    const int lane = tid & 63, wid = tid >> 6;
    if (tid == 0) s_carry = 0;
    __syncthreads();
    for (int base = 0; base < M; base += 1024) {
        const int idx = base + tid;
        const int v = (idx < M) ? hist[idx] : 0;
        int x = v;
        #pragma unroll
        for (int d = 1; d < 64; d <<= 1) {
            const int y = __shfl_up(x, d, 64);
            if (lane >= d) x += y;
        }
        if (lane == 63) wsum[wid] = x;
        __syncthreads();
        if (wid == 0) {
            int ws = (lane < 16) ? wsum[lane] : 0;
            #pragma unroll
            for (int d = 1; d < 16; d <<= 1) {
                const int y = __shfl_up(ws, d, 64);
                if (lane >= d) ws += y;
            }
            if (lane < 16) wsum[lane] = ws;
        }
        __syncthreads();
        const int waveoff = (wid == 0) ? 0 : wsum[wid - 1];
        const int carry = s_carry;
        if (idx < M) {
            offs[idx] = carry + waveoff + x - v;
            hist[idx] = 0;                       // becomes bucket cursor
        }
        const int tile_total = wsum[15];
        __syncthreads();
        if (tid == 0) s_carry = carry + tile_total;
        __syncthreads();
    }
    if (tid == 0) offs[M] = s_carry;
}

__global__ void bucket_kernel(const int* __restrict__ src, const int* __restrict__ dst,
                              const int* __restrict__ offs, int* __restrict__ cursor,
                              int* __restrict__ src_sorted, int E) {
    for (long i = (long)blockIdx.x * blockDim.x + threadIdx.x; i < E;
         i += (long)gridDim.x * blockDim.x) {
        const int d = dst[i];
        const int pos = offs[d] + atomicAdd(&cursor[d], 1);
        src_sorted[pos] = src[i];
    }
}

// ----------------------------- fp32 -> bf16 --------------------------------
__global__ void f2bf_kernel(const float* __restrict__ in, short* __restrict__ out, long n) {
    const long i = ((long)blockIdx.x * 256 + threadIdx.x) * 8;
    if (i + 8 <= n) {
        const float4 a = *(const float4*)(in + i);
        const float4 b = *(const float4*)(in + i + 4);
        *(uint4*)(out + i) = make_uint4(pack2(a.x, a.y), pack2(a.z, a.w),
                                        pack2(b.x, b.y), pack2(b.z, b.w));
    } else {
        for (long j = i; j < n; ++j) out[j] = (short)f2bf(in[j]);
    }
}

// ----------------------------- aggregation ---------------------------------
// one wave per node; lane owns 2 columns; bf16 rows gathered as dwords,
// 4 edges unrolled for load-latency hiding; fp32 accumulate.
template<int F, bool BF16_OUT>
__global__ __launch_bounds__(256)
void agg_mean_kernel(const short* __restrict__ feat, const int* __restrict__ src_sorted,
                     const int* __restrict__ offs, void* __restrict__ outv, int M) {
    const int node = blockIdx.x * 4 + (threadIdx.x >> 6);
    if (node >= M) return;
    const int lane = threadIdx.x & 63;
    const int start = offs[node], end = offs[node + 1];
    const unsigned* fb = (const unsigned*)feat;       // row stride F/2 dwords
    float2 acc = make_float2(0.f, 0.f);
    for (int e0 = start; e0 < end; e0 += 64) {
        const int n = min(64, end - e0);
        const int sv = (e0 + lane < end) ? src_sorted[e0 + lane] : 0;
        int j = 0;
        for (; j + 4 <= n; j += 4) {
            const int s0 = __shfl(sv, j, 64),     s1 = __shfl(sv, j + 1, 64);
            const int s2 = __shfl(sv, j + 2, 64), s3 = __shfl(sv, j + 3, 64);
            const unsigned u0 = fb[(long)s0 * (F / 2) + lane];
            const unsigned u1 = fb[(long)s1 * (F / 2) + lane];
            const unsigned u2 = fb[(long)s2 * (F / 2) + lane];
            const unsigned u3 = fb[(long)s3 * (F / 2) + lane];
            const float2 v0 = bfunpack(u0), v1 = bfunpack(u1);
            const float2 v2 = bfunpack(u2), v3 = bfunpack(u3);
            acc.x += (v0.x + v1.x) + (v2.x + v3.x);
            acc.y += (v0.y + v1.y) + (v2.y + v3.y);
        }
        for (; j < n; ++j) {
            const int s = __shfl(sv, j, 64);
            const float2 v = bfunpack(fb[(long)s * (F / 2) + lane]);
            acc.x += v.x; acc.y += v.y;
        }
    }
    const float inv = (end > start) ? 1.0f / (float)(end - start) : 0.f;
    acc.x *= inv; acc.y *= inv;
    if (BF16_OUT)
        ((unsigned*)outv)[(long)node * (F / 2) + lane] = pack2(acc.x, acc.y);
    else
        *reinterpret_cast<float2*>((float*)outv + (long)node * F + lane * 2) = acc;
}

// ----------------------------- weight split --------------------------------
__global__ void wsplit_kernel(const float* __restrict__ W, short* __restrict__ hi,
                              short* __restrict__ lo, int n) {
    const int i = blockIdx.x * 256 + threadIdx.x;
    if (i >= n) return;
    const float v = W[i];
    const unsigned h = f2bf(v);
    const float hf = __uint_as_float(h << 16);
    hi[i] = (short)h;
    lo[i] = (short)f2bf(v - hf);
}

// ----------------------------- MFMA GEMM -----------------------------------
// C[M][NOUT] tile 128x128, 4 waves (2x2), 16x16x32 bf16 MFMA, fp32 acc.
// A: [M][KP] bf16 shorts.  W(hi/lo): [NOUT][KP] shorts. Product a*bhi + a*blo.
template<int KP>
__device__ __forceinline__ void gemm_phase(const short* __restrict__ A,
    const short* __restrict__ Whi, const short* __restrict__ Wlo,
    int M, int row0, int col0,
    short (*As)[40], short (*Bh)[40], short (*Bl)[40], f32x4 (&acc)[4][4])
{
    const int tid = threadIdx.x;
    const int lane = tid & 63;
    const int wr = (tid >> 7) & 1, wc = (tid >> 6) & 1;
    const int l15 = lane & 15, l4 = lane >> 4;
    const int sr = tid >> 1;          // staged row 0..127
    const int sk = (tid & 1) * 16;    // k offset 0/16
    const int gr = row0 + sr;

    for (int k0 = 0; k0 < KP; k0 += 32) {
        {
            const short* ap = A + (long)gr * KP + k0 + sk;
            uint4 v0 = make_uint4(0, 0, 0, 0), v1 = make_uint4(0, 0, 0, 0);
            if (gr < M) { v0 = *(const uint4*)ap; v1 = *(const uint4*)(ap + 8); }
            *(uint4*)&As[sr][sk]     = v0;
            *(uint4*)&As[sr][sk + 8] = v1;
        }
        {
            const short* bh = Whi + (long)(col0 + sr) * KP + k0 + sk;
            const short* bl = Wlo + (long)(col0 + sr) * KP + k0 + sk;
            *(uint4*)&Bh[sr][sk]     = *(const uint4*)bh;
            *(uint4*)&Bh[sr][sk + 8] = *(const uint4*)(bh + 8);
            *(uint4*)&Bl[sr][sk]     = *(const uint4*)bl;
            *(uint4*)&Bl[sr][sk + 8] = *(const uint4*)(bl + 8);
        }
        __syncthreads();
        bf16x8 bhf[4], blf[4];
        #pragma unroll
        for (int n = 0; n < 4; ++n) {
            const int br = wc * 64 + n * 16 + l15;
            bhf[n] = *(const bf16x8*)&Bh[br][l4 * 8];
            blf[n] = *(const bf16x8*)&Bl[br][l4 * 8];
        }
        #pragma unroll
        for (int m = 0; m < 4; ++m) {
            const bf16x8 af = *(const bf16x8*)&As[wr * 64 + m * 16 + l15][l4 * 8];
            #pragma unroll
            for (int n = 0; n < 4; ++n) {
                acc[m][n] = __builtin_amdgcn_mfma_f32_16x16x32_bf16(af, bhf[n], acc[m][n], 0, 0, 0);
                acc[m][n] = __builtin_amdgcn_mfma_f32_16x16x32_bf16(af, blf[n], acc[m][n], 0, 0, 0);
            }
        }
        __syncthreads();
    }
}

template<int K1, int K2, int NOUT, bool TWO_PHASE,
         bool RELU, bool HAS_BIAS, bool EPI_ADD, bool OUT_BF16>
__global__ __launch_bounds__(256)
void mfma_gemm(const short* __restrict__ A1, const short* __restrict__ A2,
               const short* __restrict__ B1hi, const short* __restrict__ B1lo,
               const short* __restrict__ B2hi, const short* __restrict__ B2lo,
               const float* __restrict__ bias, const float* __restrict__ Epi,
               void* __restrict__ Cv, int M)
{
    __shared__ __align__(16) short As[128][40];
    __shared__ __align__(16) short Bh[128][40];
    __shared__ __align__(16) short Bl[128][40];
    const int row0 = blockIdx.x * 128, col0 = blockIdx.y * 128;
    f32x4 acc[4][4] = {};

    if constexpr (TWO_PHASE)
        gemm_phase<K1>(A1, B1hi, B1lo, M, row0, col0, As, Bh, Bl, acc);
    gemm_phase<K2>(A2, B2hi, B2lo, M, row0, col0, As, Bh, Bl, acc);

    const int tid = threadIdx.x, lane = tid & 63;
    const int wr = (tid >> 7) & 1, wc = (tid >> 6) & 1;
    const int l15 = lane & 15, l4 = lane >> 4;
    float bv[4];
    #pragma unroll
    for (int n = 0; n < 4; ++n)
        bv[n] = HAS_BIAS ? bias[col0 + wc * 64 + n * 16 + l15] : 0.f;
    #pragma unroll
    for (int m = 0; m < 4; ++m) {
        #pragma unroll
        for (int i = 0; i < 4; ++i) {
            const int r = row0 + wr * 64 + m * 16 + l4 * 4 + i;
            if (r < M) {
                #pragma unroll
                for (int n = 0; n < 4; ++n) {
                    const int c = col0 + wc * 64 + n * 16 + l15;
                    float v = acc[m][n][i] + bv[n];
                    if (EPI_ADD) v += Epi[(long)r * NOUT + c];
                    if (RELU)    v = fmaxf(v, 0.f);
                    if (OUT_BF16) ((short*)Cv)[(long)r * NOUT + c] = (short)f2bf(v);
                    else          ((float*)Cv)[(long)r * NOUT + c] = v;
                }
            }
        }
    }
}

// ----------------------------- launch --------------------------------------
extern "C" void kernel_launch(void* const* d_in, const int* in_sizes, int n_in,
                              void* d_out, int out_size, void* d_ws, size_t ws_size,
                              hipStream_t stream) {
    const float* x   = (const float*)d_in[0];
    const int*   ei  = (const int*)d_in[1];
    const float* W1l = (const float*)d_in[2];
    const float* b1  = (const float*)d_in[3];
    const float* W1r = (const float*)d_in[4];
    const float* W2l = (const float*)d_in[5];
    const float* b2  = (const float*)d_in[6];
    const float* W2r = (const float*)d_in[7];
    float* out = (float*)d_out;

    const int M = in_sizes[0] / 128;   // 50000
    const int E = in_sizes[1] / 2;     // 800000
    const int* src = ei;
    const int* dst = ei + E;

    const int Mal = ((M + 64 + 63) / 64) * 64;
    int* hist       = (int*)d_ws;                               // [Mal]
    int* offs       = hist + Mal;                               // [Mal]
    int* src_sorted = offs + Mal;                               // [E]
    float* aggbuf   = (float*)(src_sorted + ((E + 63) / 64) * 64); // [M*128] fp32 (mean2)
    short* mean1_bf = (short*)aggbuf;                           // [M*128] bf16 (aliases aggbuf)
    short* h_bf     = (short*)(aggbuf + (long)M * 128);         // [M*256] bf16
    short* wbuf     = (short*)(h_bf + (long)M * 256);           // 8 x 32768 shorts
    const int WN = 256 * 128;
    short *W1l_hi = wbuf,          *W1l_lo = wbuf + WN;
    short *W1r_hi = wbuf + 2 * WN, *W1r_lo = wbuf + 3 * WN;
    short *W2l_hi = wbuf + 4 * WN, *W2l_lo = wbuf + 5 * WN;
    short *W2r_hi = wbuf + 6 * WN, *W2r_lo = wbuf + 7 * WN;
    short* x_bf     = wbuf + 8 * WN;                            // [M*128] bf16
    short* p_bf     = (short*)out;                              // [M*128] bf16, staged in d_out

    const int TB = 256;
    // CSR build
    hipMemsetAsync(hist, 0, (size_t)Mal * sizeof(int), stream);
    hist_kernel<<<dim3((E + TB - 1) / TB), dim3(TB), 0, stream>>>(dst, hist, E);
    scan_kernel<<<dim3(1), dim3(1024), 0, stream>>>(hist, offs, M);
    bucket_kernel<<<dim3((E + TB - 1) / TB), dim3(TB), 0, stream>>>(src, dst, offs, hist, src_sorted, E);

    // x -> bf16, weight hi/lo split
    f2bf_kernel<<<dim3((int)(((long)M * 128 / 8 + TB - 1) / TB)), dim3(TB), 0, stream>>>(x, x_bf, (long)M * 128);
    const int wgrid = (WN + TB - 1) / TB;
    wsplit_kernel<<<dim3(wgrid), dim3(TB), 0, stream>>>(W1l, W1l_hi, W1l_lo, WN);
    wsplit_kernel<<<dim3(wgrid), dim3(TB), 0, stream>>>(W1r, W1r_hi, W1r_lo, WN);
    wsplit_kernel<<<dim3(wgrid), dim3(TB), 0, stream>>>(W2l, W2l_hi, W2l_lo, WN);
    wsplit_kernel<<<dim3(wgrid), dim3(TB), 0, stream>>>(W2r, W2r_hi, W2r_lo, WN);

    const int MB = (M + 127) / 128;   // 391

    // layer 1
    agg_mean_kernel<128, true><<<dim3((M + 3) / 4), dim3(TB), 0, stream>>>(x_bf, src_sorted, offs, mean1_bf, M);
    mfma_gemm<128, 128, 256, true, true, true, false, true>
        <<<dim3(MB, 2), dim3(TB), 0, stream>>>(mean1_bf, x_bf, W1l_hi, W1l_lo, W1r_hi, W1r_lo,
                                               b1, nullptr, h_bf, M);
    // layer 2
    mfma_gemm<128, 256, 128, false, false, false, false, true>
        <<<dim3(MB, 1), dim3(TB), 0, stream>>>(nullptr, h_bf, nullptr, nullptr, W2l_hi, W2l_lo,
                                               nullptr, nullptr, p_bf, M);
    agg_mean_kernel<128, false><<<dim3((M + 3) / 4), dim3(TB), 0, stream>>>(p_bf, src_sorted, offs, aggbuf, M);
    mfma_gemm<128, 256, 128, false, false, true, true, false>
        <<<dim3(MB, 1), dim3(TB), 0, stream>>>(nullptr, h_bf, nullptr, nullptr, W2r_hi, W2r_lo,
                                               b2, aggbuf, out, M);
}

// Round 7
// 312.582 us; speedup vs baseline: 9.6470x; 1.1280x over previous
//
#include <hip/hip_runtime.h>

// ---------------------------------------------------------------------------
// 2-layer GraphSAGE (mean aggr), CSR-pull aggregation + bf16-MFMA GEMMs.
//   CSR build: hist -> 3-phase parallel scan -> bucket (src_sorted by dst)
//   x_bf = bf16(x); weights split hi/lo bf16 (2 MFMAs kill B-rounding)
//   mean1 = mean_agg(x_bf)                      -> bf16   [M,128]
//   h     = relu(mean1@W1l^T + b1 + x_bf@W1r^T) -> bf16   [M,256]  (MFMA)
//   {p, out0} = h @ {W2l,W2r}^T  (dual GEMM, h staged once)
//        p -> bf16 (ws), out0 = h@W2r^T+b2 -> fp32 (d_out)
//   out  += mean_agg(p)   (in-place add, one wave per node)
// ws: hist|offs+bsum|src_sorted | mean1_bf 12.8MB | p_bf 12.8MB
//     | h_bf 25.6MB | wbuf 0.5MB | x_bf 12.8MB     total ~68MB
// ---------------------------------------------------------------------------

typedef short bf16x8 __attribute__((ext_vector_type(8)));
typedef float f32x4  __attribute__((ext_vector_type(4)));

__device__ __forceinline__ unsigned f2bf(float f) {         // RNE fp32->bf16 bits
    unsigned u = __float_as_uint(f);
    return (u + 0x7FFFu + ((u >> 16) & 1u)) >> 16;
}
__device__ __forceinline__ unsigned pack2(float a, float b) {
    return f2bf(a) | (f2bf(b) << 16);
}
__device__ __forceinline__ float2 bfunpack(unsigned u) {    // (low, high) bf16 -> fp32
    return make_float2(__uint_as_float(u << 16), __uint_as_float(u & 0xffff0000u));
}

// ----------------------------- CSR build -----------------------------------
__global__ void hist_kernel(const int* __restrict__ dst, int* __restrict__ hist, int E) {
    for (long i = (long)blockIdx.x * blockDim.x + threadIdx.x; i < E;
         i += (long)gridDim.x * blockDim.x)
        atomicAdd(&hist[dst[i]], 1);
}

// 3-phase scan over hist[0..M): 2048 elems/block, 8/thread
__global__ __launch_bounds__(256)
void scan_reduce_kernel(const int* __restrict__ hist, int* __restrict__ bsum, int M) {
    const long base = (long)blockIdx.x * 2048 + (long)threadIdx.x * 8;
    int s = 0;
    #pragma unroll
    for (int i = 0; i < 8; ++i) { const long idx = base + i; if (idx < M) s += hist[idx]; }
    #pragma unroll
    for (int d = 32; d; d >>= 1) s += __shfl_down(s, d, 64);
    __shared__ int ws[4];
    const int lane = threadIdx.x & 63, wid = threadIdx.x >> 6;
    if (lane == 0) ws[wid] = s;
    __syncthreads();
    if (threadIdx.x == 0) bsum[blockIdx.x] = ws[0] + ws[1] + ws[2] + ws[3];
}

__global__ void scan_root_kernel(int* __restrict__ bsum, int NB) {   // NB <= 64, 64 threads
    const int lane = threadIdx.x;
    const int v = (lane < NB) ? bsum[lane] : 0;
    int x = v;
    #pragma unroll
    for (int d = 1; d < 64; d <<= 1) { const int y = __shfl_up(x, d, 64); if (lane >= d) x += y; }
    if (lane < NB) bsum[lane] = x - v;   // exclusive
}

__global__ __launch_bounds__(256)
void scan_apply_kernel(int* __restrict__ hist, const int* __restrict__ bsum,
                       int* __restrict__ offs, int M, int E) {
    const long base = (long)blockIdx.x * 2048 + (long)threadIdx.x * 8;
    int v[8];
    #pragma unroll
    for (int i = 0; i < 8; ++i) { const long idx = base + i; v[i] = (idx < M) ? hist[idx] : 0; }
    int tsum = 0;
    #pragma unroll
    for (int i = 0; i < 8; ++i) { const int t = v[i]; v[i] = tsum; tsum += t; }
    const int lane = threadIdx.x & 63, wid = threadIdx.x >> 6;
    int x = tsum;
    #pragma unroll
    for (int d = 1; d < 64; d <<= 1) { const int y = __shfl_up(x, d, 64); if (lane >= d) x += y; }
    __shared__ int ws[4];
    if (lane == 63) ws[wid] = x;
    __syncthreads();
    int woff = bsum[blockIdx.x];
    if (wid > 0) woff += ws[0];
    if (wid > 1) woff += ws[1];
    if (wid > 2) woff += ws[2];
    const int texcl = woff + x - tsum;
    #pragma unroll
    for (int i = 0; i < 8; ++i) {
        const long idx = base + i;
        if (idx < M) { offs[idx] = texcl + v[i]; hist[idx] = 0; }   // hist becomes cursor
    }
    if (blockIdx.x == 0 && threadIdx.x == 0) offs[M] = E;
}

__global__ void bucket_kernel(const int* __restrict__ src, const int* __restrict__ dst,
                              const int* __restrict__ offs, int* __restrict__ cursor,
                              int* __restrict__ src_sorted, int E) {
    for (long i = (long)blockIdx.x * blockDim.x + threadIdx.x; i < E;
         i += (long)gridDim.x * blockDim.x) {
        const int d = dst[i];
        const int pos = offs[d] + atomicAdd(&cursor[d], 1);
        src_sorted[pos] = src[i];
    }
}

// ----------------------------- fp32 -> bf16 --------------------------------
__global__ void f2bf_kernel(const float* __restrict__ in, short* __restrict__ out, long n) {
    const long i = ((long)blockIdx.x * 256 + threadIdx.x) * 8;
    if (i + 8 <= n) {
        const float4 a = *(const float4*)(in + i);
        const float4 b = *(const float4*)(in + i + 4);
        *(uint4*)(out + i) = make_uint4(pack2(a.x, a.y), pack2(a.z, a.w),
                                        pack2(b.x, b.y), pack2(b.z, b.w));
    } else {
        for (long j = i; j < n; ++j) out[j] = (short)f2bf(in[j]);
    }
}

// ----------------------------- weight split (4 at once) --------------------
__global__ void wsplit4_kernel(const float* __restrict__ W0, const float* __restrict__ W1,
                               const float* __restrict__ W2, const float* __restrict__ W3,
                               short* __restrict__ wbuf, int n) {
    const int w = blockIdx.y;
    const float* __restrict__ W = (w == 0) ? W0 : (w == 1) ? W1 : (w == 2) ? W2 : W3;
    short* hi = wbuf + (long)(2 * w) * n;
    short* lo = hi + n;
    const int i = blockIdx.x * 256 + threadIdx.x;
    if (i >= n) return;
    const float v = W[i];
    const unsigned h = f2bf(v);
    hi[i] = (short)h;
    lo[i] = (short)f2bf(v - __uint_as_float(h << 16));
}

// ----------------------------- aggregation ---------------------------------
// one wave per node; lane owns 2 columns (1 dword of bf16); 4x edge unroll.
// BF16_OUT: store mean as bf16.  ADD: out(fp32) += mean (read-modify-write).
template<int F, bool BF16_OUT, bool ADD>
__global__ __launch_bounds__(256)
void agg_mean_kernel(const short* __restrict__ feat, const int* __restrict__ src_sorted,
                     const int* __restrict__ offs, void* __restrict__ outv, int M) {
    const int node = blockIdx.x * 4 + (threadIdx.x >> 6);
    if (node >= M) return;
    const int lane = threadIdx.x & 63;
    const int start = offs[node], end = offs[node + 1];
    const unsigned* fb = (const unsigned*)feat;       // row stride F/2 dwords
    float2 acc = make_float2(0.f, 0.f);
    for (int e0 = start; e0 < end; e0 += 64) {
        const int n = min(64, end - e0);
        const int sv = (e0 + lane < end) ? src_sorted[e0 + lane] : 0;
        int j = 0;
        for (; j + 4 <= n; j += 4) {
            const int s0 = __shfl(sv, j, 64),     s1 = __shfl(sv, j + 1, 64);
            const int s2 = __shfl(sv, j + 2, 64), s3 = __shfl(sv, j + 3, 64);
            const unsigned u0 = fb[(long)s0 * (F / 2) + lane];
            const unsigned u1 = fb[(long)s1 * (F / 2) + lane];
            const unsigned u2 = fb[(long)s2 * (F / 2) + lane];
            const unsigned u3 = fb[(long)s3 * (F / 2) + lane];
            const float2 v0 = bfunpack(u0), v1 = bfunpack(u1);
            const float2 v2 = bfunpack(u2), v3 = bfunpack(u3);
            acc.x += (v0.x + v1.x) + (v2.x + v3.x);
            acc.y += (v0.y + v1.y) + (v2.y + v3.y);
        }
        for (; j < n; ++j) {
            const int s = __shfl(sv, j, 64);
            const float2 v = bfunpack(fb[(long)s * (F / 2) + lane]);
            acc.x += v.x; acc.y += v.y;
        }
    }
    const float inv = (end > start) ? 1.0f / (float)(end - start) : 0.f;
    acc.x *= inv; acc.y *= inv;
    if (BF16_OUT) {
        ((unsigned*)outv)[(long)node * (F / 2) + lane] = pack2(acc.x, acc.y);
    } else if (ADD) {
        float2* op = reinterpret_cast<float2*>((float*)outv + (long)node * F + lane * 2);
        const float2 cur = *op;
        *op = make_float2(cur.x + acc.x, cur.y + acc.y);
    } else {
        *reinterpret_cast<float2*>((float*)outv + (long)node * F + lane * 2) = acc;
    }
}

// ----------------------------- MFMA GEMM (layer 1) -------------------------
// C[M][NOUT] tile 128x128, 4 waves (2x2), 16x16x32 bf16 MFMA, fp32 acc.
template<int KP>
__device__ __forceinline__ void gemm_phase(const short* __restrict__ A,
    const short* __restrict__ Whi, const short* __restrict__ Wlo,
    int M, int row0, int col0,
    short (*As)[40], short (*Bh)[40], short (*Bl)[40], f32x4 (&acc)[4][4])
{
    const int tid = threadIdx.x;
    const int lane = tid & 63;
    const int wr = (tid >> 7) & 1, wc = (tid >> 6) & 1;
    const int l15 = lane & 15, l4 = lane >> 4;
    const int sr = tid >> 1;
    const int sk = (tid & 1) * 16;
    const int gr = row0 + sr;

    for (int k0 = 0; k0 < KP; k0 += 32) {
        {
            const short* ap = A + (long)gr * KP + k0 + sk;
            uint4 v0 = make_uint4(0, 0, 0, 0), v1 = make_uint4(0, 0, 0, 0);
            if (gr < M) { v0 = *(const uint4*)ap; v1 = *(const uint4*)(ap + 8); }
            *(uint4*)&As[sr][sk]     = v0;
            *(uint4*)&As[sr][sk + 8] = v1;
        }
        {
            const short* bh = Whi + (long)(col0 + sr) * KP + k0 + sk;
            const short* bl = Wlo + (long)(col0 + sr) * KP + k0 + sk;
            *(uint4*)&Bh[sr][sk]     = *(const uint4*)bh;
            *(uint4*)&Bh[sr][sk + 8] = *(const uint4*)(bh + 8);
            *(uint4*)&Bl[sr][sk]     = *(const uint4*)bl;
            *(uint4*)&Bl[sr][sk + 8] = *(const uint4*)(bl + 8);
        }
        __syncthreads();
        bf16x8 bhf[4], blf[4];
        #pragma unroll
        for (int n = 0; n < 4; ++n) {
            const int br = wc * 64 + n * 16 + l15;
            bhf[n] = *(const bf16x8*)&Bh[br][l4 * 8];
            blf[n] = *(const bf16x8*)&Bl[br][l4 * 8];
        }
        #pragma unroll
        for (int m = 0; m < 4; ++m) {
            const bf16x8 af = *(const bf16x8*)&As[wr * 64 + m * 16 + l15][l4 * 8];
            #pragma unroll
            for (int n = 0; n < 4; ++n) {
                acc[m][n] = __builtin_amdgcn_mfma_f32_16x16x32_bf16(af, bhf[n], acc[m][n], 0, 0, 0);
                acc[m][n] = __builtin_amdgcn_mfma_f32_16x16x32_bf16(af, blf[n], acc[m][n], 0, 0, 0);
            }
        }
        __syncthreads();
    }
}

template<int K1, int K2, int NOUT, bool TWO_PHASE,
         bool RELU, bool HAS_BIAS, bool OUT_BF16>
__global__ __launch_bounds__(256)
void mfma_gemm(const short* __restrict__ A1, const short* __restrict__ A2,
               const short* __restrict__ B1hi, const short* __restrict__ B1lo,
               const short* __restrict__ B2hi, const short* __restrict__ B2lo,
               const float* __restrict__ bias, void* __restrict__ Cv, int M)
{
    __shared__ __align__(16) short As[128][40];
    __shared__ __align__(16) short Bh[128][40];
    __shared__ __align__(16) short Bl[128][40];
    const int row0 = blockIdx.x * 128, col0 = blockIdx.y * 128;
    f32x4 acc[4][4] = {};

    if constexpr (TWO_PHASE)
        gemm_phase<K1>(A1, B1hi, B1lo, M, row0, col0, As, Bh, Bl, acc);
    gemm_phase<K2>(A2, B2hi, B2lo, M, row0, col0, As, Bh, Bl, acc);

    const int tid = threadIdx.x, lane = tid & 63;
    const int wr = (tid >> 7) & 1, wc = (tid >> 6) & 1;
    const int l15 = lane & 15, l4 = lane >> 4;
    float bv[4];
    #pragma unroll
    for (int n = 0; n < 4; ++n)
        bv[n] = HAS_BIAS ? bias[col0 + wc * 64 + n * 16 + l15] : 0.f;
    #pragma unroll
    for (int m = 0; m < 4; ++m) {
        #pragma unroll
        for (int i = 0; i < 4; ++i) {
            const int r = row0 + wr * 64 + m * 16 + l4 * 4 + i;
            if (r < M) {
                #pragma unroll
                for (int n = 0; n < 4; ++n) {
                    const int c = col0 + wc * 64 + n * 16 + l15;
                    float v = acc[m][n][i] + bv[n];
                    if (RELU) v = fmaxf(v, 0.f);
                    if (OUT_BF16) ((short*)Cv)[(long)r * NOUT + c] = (short)f2bf(v);
                    else          ((float*)Cv)[(long)r * NOUT + c] = v;
                }
            }
        }
    }
}

// ----------------------------- dual MFMA GEMM (layer 2) --------------------
// Stages A (h_bf) once; computes A@Wa^T -> Ca (bf16) and A@Wb^T + bias -> Cb (fp32).
template<int K, int NOUT>
__global__ __launch_bounds__(256)
void mfma_gemm_dual(const short* __restrict__ A,
                    const short* __restrict__ Wahi, const short* __restrict__ Walo,
                    const short* __restrict__ Wbhi, const short* __restrict__ Wblo,
                    const float* __restrict__ bias, short* __restrict__ Ca,
                    float* __restrict__ Cb, int M)
{
    __shared__ __align__(16) short As[128][40];
    __shared__ __align__(16) short Bh[2][128][40];
    __shared__ __align__(16) short Bl[2][128][40];
    const int row0 = blockIdx.x * 128;
    f32x4 acc[2][4][4] = {};

    const int tid = threadIdx.x, lane = tid & 63;
    const int wr = (tid >> 7) & 1, wc = (tid >> 6) & 1;
    const int l15 = lane & 15, l4 = lane >> 4;
    const int sr = tid >> 1;
    const int sk = (tid & 1) * 16;
    const int gr = row0 + sr;

    for (int k0 = 0; k0 < K; k0 += 32) {
        {
            const short* ap = A + (long)gr * K + k0 + sk;
            uint4 v0 = make_uint4(0, 0, 0, 0), v1 = make_uint4(0, 0, 0, 0);
            if (gr < M) { v0 = *(const uint4*)ap; v1 = *(const uint4*)(ap + 8); }
            *(uint4*)&As[sr][sk]     = v0;
            *(uint4*)&As[sr][sk + 8] = v1;
        }
        {
            const short* bh0 = Wahi + (long)sr * K + k0 + sk;
            const short* bl0 = Walo + (long)sr * K + k0 + sk;
            const short* bh1 = Wbhi + (long)sr * K + k0 + sk;
            const short* bl1 = Wblo + (long)sr * K + k0 + sk;
            *(uint4*)&Bh[0][sr][sk]     = *(const uint4*)bh0;
            *(uint4*)&Bh[0][sr][sk + 8] = *(const uint4*)(bh0 + 8);
            *(uint4*)&Bl[0][sr][sk]     = *(const uint4*)bl0;
            *(uint4*)&Bl[0][sr][sk + 8] = *(const uint4*)(bl0 + 8);
            *(uint4*)&Bh[1][sr][sk]     = *(const uint4*)bh1;
            *(uint4*)&Bh[1][sr][sk + 8] = *(const uint4*)(bh1 + 8);
            *(uint4*)&Bl[1][sr][sk]     = *(const uint4*)bl1;
            *(uint4*)&Bl[1][sr][sk + 8] = *(const uint4*)(bl1 + 8);
        }
        __syncthreads();
        bf16x8 af[4];
        #pragma unroll
        for (int m = 0; m < 4; ++m)
            af[m] = *(const bf16x8*)&As[wr * 64 + m * 16 + l15][l4 * 8];
        #pragma unroll
        for (int w = 0; w < 2; ++w) {
            #pragma unroll
            for (int n = 0; n < 4; ++n) {
                const int br = wc * 64 + n * 16 + l15;
                const bf16x8 bhf = *(const bf16x8*)&Bh[w][br][l4 * 8];
                const bf16x8 blf = *(const bf16x8*)&Bl[w][br][l4 * 8];
                #pragma unroll
                for (int m = 0; m < 4; ++m) {
                    acc[w][m][n] = __builtin_amdgcn_mfma_f32_16x16x32_bf16(af[m], bhf, acc[w][m][n], 0, 0, 0);
                    acc[w][m][n] = __builtin_amdgcn_mfma_f32_16x16x32_bf16(af[m], blf, acc[w][m][n], 0, 0, 0);
                }
            }
        }
        __syncthreads();
    }

    float bv[4];
    #pragma unroll
    for (int n = 0; n < 4; ++n)
        bv[n] = bias[wc * 64 + n * 16 + l15];
    #pragma unroll
    for (int m = 0; m < 4; ++m) {
        #pragma unroll
        for (int i = 0; i < 4; ++i) {
            const int r = row0 + wr * 64 + m * 16 + l4 * 4 + i;
            if (r < M) {
                #pragma unroll
                for (int n = 0; n < 4; ++n) {
                    const int c = wc * 64 + n * 16 + l15;
                    Ca[(long)r * NOUT + c] = (short)f2bf(acc[0][m][n][i]);
                    Cb[(long)r * NOUT + c] = acc[1][m][n][i] + bv[n];
                }
            }
        }
    }
}

// ----------------------------- launch --------------------------------------
extern "C" void kernel_launch(void* const* d_in, const int* in_sizes, int n_in,
                              void* d_out, int out_size, void* d_ws, size_t ws_size,
                              hipStream_t stream) {
    const float* x   = (const float*)d_in[0];
    const int*   ei  = (const int*)d_in[1];
    const float* W1l = (const float*)d_in[2];
    const float* b1  = (const float*)d_in[3];
    const float* W1r = (const float*)d_in[4];
    const float* W2l = (const float*)d_in[5];
    const float* b2  = (const float*)d_in[6];
    const float* W2r = (const float*)d_in[7];
    float* out = (float*)d_out;

    const int M = in_sizes[0] / 128;   // 50000
    const int E = in_sizes[1] / 2;     // 800000
    const int* src = ei;
    const int* dst = ei + E;

    const int Mal = ((M + 64 + 63) / 64) * 64;
    int* hist       = (int*)d_ws;                               // [Mal]
    int* offs       = hist + Mal;                               // [M+1] (+ bsum slack)
    int* bsum       = offs + ((M + 1 + 63) / 64) * 64;          // [<=64]
    int* src_sorted = offs + Mal;                               // [E]
    short* mean1_bf = (short*)(src_sorted + ((E + 63) / 64) * 64); // [M*128] bf16
    short* p_bf     = mean1_bf + (long)M * 128;                 // [M*128] bf16
    short* h_bf     = p_bf + (long)M * 128;                     // [M*256] bf16
    short* wbuf     = h_bf + (long)M * 256;                     // 8 x 32768 shorts
    const int WN = 256 * 128;
    short *W1l_hi = wbuf,          *W1l_lo = wbuf + WN;
    short *W1r_hi = wbuf + 2 * WN, *W1r_lo = wbuf + 3 * WN;
    short *W2l_hi = wbuf + 4 * WN, *W2l_lo = wbuf + 5 * WN;
    short *W2r_hi = wbuf + 6 * WN, *W2r_lo = wbuf + 7 * WN;
    short* x_bf     = wbuf + 8 * WN;                            // [M*128] bf16

    const int TB = 256;
    const int NB = (M + 2047) / 2048;   // 25 scan blocks

    // CSR build
    hipMemsetAsync(hist, 0, (size_t)Mal * sizeof(int), stream);
    hist_kernel<<<dim3((E + TB - 1) / TB), dim3(TB), 0, stream>>>(dst, hist, E);
    scan_reduce_kernel<<<dim3(NB), dim3(TB), 0, stream>>>(hist, bsum, M);
    scan_root_kernel<<<dim3(1), dim3(64), 0, stream>>>(bsum, NB);
    scan_apply_kernel<<<dim3(NB), dim3(TB), 0, stream>>>(hist, bsum, offs, M, E);
    bucket_kernel<<<dim3((E + TB - 1) / TB), dim3(TB), 0, stream>>>(src, dst, offs, hist, src_sorted, E);

    // x -> bf16, weight hi/lo splits (fused)
    f2bf_kernel<<<dim3((int)(((long)M * 128 / 8 + TB - 1) / TB)), dim3(TB), 0, stream>>>(x, x_bf, (long)M * 128);
    wsplit4_kernel<<<dim3((WN + TB - 1) / TB, 4), dim3(TB), 0, stream>>>(W1l, W1r, W2l, W2r, wbuf, WN);

    const int MB = (M + 127) / 128;   // 391

    // layer 1
    agg_mean_kernel<128, true, false><<<dim3((M + 3) / 4), dim3(TB), 0, stream>>>(x_bf, src_sorted, offs, mean1_bf, M);
    mfma_gemm<128, 128, 256, true, true, true, true>
        <<<dim3(MB, 2), dim3(TB), 0, stream>>>(mean1_bf, x_bf, W1l_hi, W1l_lo, W1r_hi, W1r_lo,
                                               b1, h_bf, M);
    // layer 2: p = h@W2l^T (bf16), out = h@W2r^T + b2 (fp32), h staged once
    mfma_gemm_dual<256, 128>
        <<<dim3(MB), dim3(TB), 0, stream>>>(h_bf, W2l_hi, W2l_lo, W2r_hi, W2r_lo,
                                            b2, p_bf, out, M);
    // out += mean_agg(p)
    agg_mean_kernel<128, false, true><<<dim3((M + 3) / 4), dim3(TB), 0, stream>>>(p_bf, src_sorted, offs, out, M);
}

// Round 8
// 278.462 us; speedup vs baseline: 10.8291x; 1.1225x over previous
//
#include <hip/hip_runtime.h>

// ---------------------------------------------------------------------------
// 2-layer GraphSAGE (mean aggr), CSR-pull aggregation + bf16-MFMA GEMMs.
//   prep: x->bf16, weight hi/lo split, dst histogram        (one fused kernel)
//   scan: 3-phase parallel exclusive scan -> offs (+ per-bucket bases gcur)
//   msplit: block-local LDS sort by dst>>8, coalesced run flush -> staging
//   bsort: per-bucket LDS counting sort by dst -> src_sorted (coalesced)
//   mean1 = mean_agg(x_bf)                      -> bf16   [M,128]
//   h     = relu(mean1@W1l^T + b1 + x_bf@W1r^T) -> bf16   [M,256]  (MFMA)
//   {p, out0} = h @ {W2l,W2r}^T (dual GEMM)  p->bf16, out0=h@W2r^T+b2 (fp32)
//   out  += mean_agg(p)
// ws: hist|offs|bsum|gcur | staging(uint2 E) | src_sorted[E]
//     | mean1_bf | p_bf | h_bf | wbuf | x_bf    total ~74.5MB
// ---------------------------------------------------------------------------

typedef short bf16x8 __attribute__((ext_vector_type(8)));
typedef float f32x4  __attribute__((ext_vector_type(4)));

__device__ __forceinline__ unsigned f2bf(float f) {         // RNE fp32->bf16 bits
    unsigned u = __float_as_uint(f);
    return (u + 0x7FFFu + ((u >> 16) & 1u)) >> 16;
}
__device__ __forceinline__ unsigned pack2(float a, float b) {
    return f2bf(a) | (f2bf(b) << 16);
}
__device__ __forceinline__ float2 bfunpack(unsigned u) {    // (low, high) bf16 -> fp32
    return make_float2(__uint_as_float(u << 16), __uint_as_float(u & 0xffff0000u));
}

// exclusive scan of 256 ints in LDS (wave 0 only; caller syncs)
__device__ __forceinline__ void scan256(const int* __restrict__ h,
                                        int* __restrict__ out, int tid) {
    if (tid < 64) {
        const int i4 = tid * 4;
        const int v0 = h[i4], v1 = h[i4 + 1], v2 = h[i4 + 2], v3 = h[i4 + 3];
        const int t = v0 + v1 + v2 + v3;
        int x = t;
        #pragma unroll
        for (int dd = 1; dd < 64; dd <<= 1) {
            const int y = __shfl_up(x, dd, 64);
            if (tid >= dd) x += y;
        }
        const int ex = x - t;
        out[i4] = ex; out[i4 + 1] = ex + v0;
        out[i4 + 2] = ex + v0 + v1; out[i4 + 3] = ex + v0 + v1 + v2;
    }
}

// ----------------------------- fused prep ----------------------------------
// roles by blockIdx.x: [0,nbF) f2bf | [nbF,nbF+nbW) wsplit | rest: hist
__global__ __launch_bounds__(256)
void prep_kernel(const float* __restrict__ x, short* __restrict__ x_bf, long nx,
                 const float* __restrict__ W0, const float* __restrict__ W1,
                 const float* __restrict__ W2, const float* __restrict__ W3,
                 short* __restrict__ wbuf, int wn,
                 const int* __restrict__ dst, int* __restrict__ hist, int E,
                 int nbF, int nbW) {
    const int bx = blockIdx.x, tid = threadIdx.x;
    if (bx < nbF) {
        const long i = ((long)bx * 256 + tid) * 8;
        if (i + 8 <= nx) {
            const float4 a = *(const float4*)(x + i);
            const float4 b = *(const float4*)(x + i + 4);
            *(uint4*)(x_bf + i) = make_uint4(pack2(a.x, a.y), pack2(a.z, a.w),
                                             pack2(b.x, b.y), pack2(b.z, b.w));
        }
    } else if (bx < nbF + nbW) {
        const int rel = bx - nbF;
        const int w = rel >> 7;                  // 128 blocks per weight
        const float* __restrict__ W = (w == 0) ? W0 : (w == 1) ? W1 : (w == 2) ? W2 : W3;
        short* hi = wbuf + (long)(2 * w) * wn;
        short* lo = hi + wn;
        const int i = (rel & 127) * 256 + tid;
        if (i < wn) {
            const float v = W[i];
            const unsigned h = f2bf(v);
            hi[i] = (short)h;
            lo[i] = (short)f2bf(v - __uint_as_float(h << 16));
        }
    } else {
        const int hb = bx - nbF - nbW;
        #pragma unroll
        for (int k = 0; k < 4; ++k) {
            const int i = hb * 1024 + k * 256 + tid;
            if (i < E) atomicAdd(&hist[dst[i]], 1);
        }
    }
}

// ----------------------------- 3-phase scan --------------------------------
__global__ __launch_bounds__(256)
void scan_reduce_kernel(const int* __restrict__ hist, int* __restrict__ bsum, int M) {
    const long base = (long)blockIdx.x * 2048 + (long)threadIdx.x * 8;
    int s = 0;
    #pragma unroll
    for (int i = 0; i < 8; ++i) { const long idx = base + i; if (idx < M) s += hist[idx]; }
    #pragma unroll
    for (int d = 32; d; d >>= 1) s += __shfl_down(s, d, 64);
    __shared__ int ws[4];
    const int lane = threadIdx.x & 63, wid = threadIdx.x >> 6;
    if (lane == 0) ws[wid] = s;
    __syncthreads();
    if (threadIdx.x == 0) bsum[blockIdx.x] = ws[0] + ws[1] + ws[2] + ws[3];
}

__global__ void scan_root_kernel(int* __restrict__ bsum, int NB) {   // NB <= 64
    const int lane = threadIdx.x;
    const int v = (lane < NB) ? bsum[lane] : 0;
    int x = v;
    #pragma unroll
    for (int d = 1; d < 64; d <<= 1) { const int y = __shfl_up(x, d, 64); if (lane >= d) x += y; }
    if (lane < NB) bsum[lane] = x - v;   // exclusive
}

__global__ __launch_bounds__(256)
void scan_apply_kernel(int* __restrict__ hist, const int* __restrict__ bsum,
                       int* __restrict__ offs, int* __restrict__ gcur, int M, int E) {
    const long base = (long)blockIdx.x * 2048 + (long)threadIdx.x * 8;
    int v[8];
    #pragma unroll
    for (int i = 0; i < 8; ++i) { const long idx = base + i; v[i] = (idx < M) ? hist[idx] : 0; }
    int tsum = 0;
    #pragma unroll
    for (int i = 0; i < 8; ++i) { const int t = v[i]; v[i] = tsum; tsum += t; }
    const int lane = threadIdx.x & 63, wid = threadIdx.x >> 6;
    int x = tsum;
    #pragma unroll
    for (int d = 1; d < 64; d <<= 1) { const int y = __shfl_up(x, d, 64); if (lane >= d) x += y; }
    __shared__ int ws[4];
    if (lane == 63) ws[wid] = x;
    __syncthreads();
    int woff = bsum[blockIdx.x];
    if (wid > 0) woff += ws[0];
    if (wid > 1) woff += ws[1];
    if (wid > 2) woff += ws[2];
    const int texcl = woff + x - tsum;
    #pragma unroll
    for (int i = 0; i < 8; ++i) {
        const long idx = base + i;
        if (idx < M) {
            const int o = texcl + v[i];
            offs[idx] = o;
            hist[idx] = 0;                               // becomes fallback cursor
            if ((idx & 255) == 0) gcur[idx >> 8] = o;    // coarse-bucket base
        }
    }
    if (blockIdx.x == 0 && threadIdx.x == 0) offs[M] = E;
}

// ----------------------------- coarse multisplit ---------------------------
// 4096 edges/block; LDS counting sort by dst>>8; coalesced run flush.
__global__ __launch_bounds__(1024)
void msplit_kernel(const int* __restrict__ src, const int* __restrict__ dst,
                   int* __restrict__ gcur, uint2* __restrict__ staging, int E) {
    __shared__ int hist[256], scanex[256], gb[256];
    __shared__ uint2 pairs[4096];
    const int tid = threadIdx.x;
    const long base = (long)blockIdx.x * 4096;
    const int cnt = min(4096, (int)(E - base));
    if (tid < 256) hist[tid] = 0;
    __syncthreads();
    int d[4], s[4];
    #pragma unroll
    for (int k = 0; k < 4; ++k) {
        const int i = tid + k * 1024;
        if (i < cnt) {
            d[k] = dst[base + i]; s[k] = src[base + i];
            atomicAdd(&hist[d[k] >> 8], 1);
        }
    }
    __syncthreads();
    scan256(hist, scanex, tid);
    __syncthreads();
    if (tid < 256) {
        const int c = hist[tid];
        gb[tid] = c ? atomicAdd(&gcur[tid], c) : 0;
        hist[tid] = scanex[tid];                 // becomes LDS cursor
    }
    __syncthreads();
    #pragma unroll
    for (int k = 0; k < 4; ++k) {
        const int i = tid + k * 1024;
        if (i < cnt) {
            const int b = d[k] >> 8;
            const int pos = atomicAdd(&hist[b], 1);
            pairs[pos] = make_uint2((unsigned)s[k], (unsigned)d[k]);
        }
    }
    __syncthreads();
    #pragma unroll
    for (int k = 0; k < 4; ++k) {
        const int i = tid + k * 1024;
        if (i < cnt) {
            const uint2 pr = pairs[i];
            const int b = (int)(pr.y >> 8);
            staging[gb[b] + (i - scanex[b])] = pr;    // bucket-contiguous runs
        }
    }
}

// ----------------------------- per-bucket sort -----------------------------
// one block per 256-node bucket; LDS counting sort by exact dst; coalesced out.
__global__ __launch_bounds__(1024)
void bsort_kernel(const uint2* __restrict__ staging, const int* __restrict__ offs,
                  int* __restrict__ fb_cur, int* __restrict__ src_sorted, int M) {
    const int b = blockIdx.x;
    const int n0 = b * 256;
    const int n1 = min(n0 + 256, M);
    const int s0 = offs[n0], s1 = offs[n1];
    const int cnt = s1 - s0;
    const int tid = threadIdx.x;
    if (cnt > 8192) {        // fallback (degenerate degree distributions)
        for (int i = tid; i < cnt; i += 1024) {
            const uint2 pr = staging[s0 + i];
            const int pos = offs[pr.y] + atomicAdd(&fb_cur[pr.y], 1);
            src_sorted[pos] = (int)pr.x;
        }
        return;
    }
    __shared__ int hist[256], base2[256];
    __shared__ int lsrc[8192];
    if (tid < 256) hist[tid] = 0;
    __syncthreads();
    for (int i = tid; i < cnt; i += 1024)
        atomicAdd(&hist[staging[s0 + i].y & 255], 1);
    __syncthreads();
    scan256(hist, base2, tid);
    __syncthreads();
    if (tid < 256) hist[tid] = base2[tid];       // cursor
    __syncthreads();
    for (int i = tid; i < cnt; i += 1024) {
        const uint2 pr = staging[s0 + i];
        const int pos = atomicAdd(&hist[pr.y & 255], 1);
        lsrc[pos] = (int)pr.x;
    }
    __syncthreads();
    for (int i = tid; i < cnt; i += 1024)
        src_sorted[s0 + i] = lsrc[i];            // fully coalesced
}

// ----------------------------- aggregation ---------------------------------
template<int F, bool BF16_OUT, bool ADD>
__global__ __launch_bounds__(256)
void agg_mean_kernel(const short* __restrict__ feat, const int* __restrict__ src_sorted,
                     const int* __restrict__ offs, void* __restrict__ outv, int M) {
    const int node = blockIdx.x * 4 + (threadIdx.x >> 6);
    if (node >= M) return;
    const int lane = threadIdx.x & 63;
    const int start = offs[node], end = offs[node + 1];
    const unsigned* fb = (const unsigned*)feat;       // row stride F/2 dwords
    float2 acc = make_float2(0.f, 0.f);
    for (int e0 = start; e0 < end; e0 += 64) {
        const int n = min(64, end - e0);
        const int sv = (e0 + lane < end) ? src_sorted[e0 + lane] : 0;
        int j = 0;
        for (; j + 4 <= n; j += 4) {
            const int s0 = __shfl(sv, j, 64),     s1 = __shfl(sv, j + 1, 64);
            const int s2 = __shfl(sv, j + 2, 64), s3 = __shfl(sv, j + 3, 64);
            const unsigned u0 = fb[(long)s0 * (F / 2) + lane];
            const unsigned u1 = fb[(long)s1 * (F / 2) + lane];
            const unsigned u2 = fb[(long)s2 * (F / 2) + lane];
            const unsigned u3 = fb[(long)s3 * (F / 2) + lane];
            const float2 v0 = bfunpack(u0), v1 = bfunpack(u1);
            const float2 v2 = bfunpack(u2), v3 = bfunpack(u3);
            acc.x += (v0.x + v1.x) + (v2.x + v3.x);
            acc.y += (v0.y + v1.y) + (v2.y + v3.y);
        }
        for (; j < n; ++j) {
            const int s = __shfl(sv, j, 64);
            const float2 v = bfunpack(fb[(long)s * (F / 2) + lane]);
            acc.x += v.x; acc.y += v.y;
        }
    }
    const float inv = (end > start) ? 1.0f / (float)(end - start) : 0.f;
    acc.x *= inv; acc.y *= inv;
    if (BF16_OUT) {
        ((unsigned*)outv)[(long)node * (F / 2) + lane] = pack2(acc.x, acc.y);
    } else if (ADD) {
        float2* op = reinterpret_cast<float2*>((float*)outv + (long)node * F + lane * 2);
        const float2 cur = *op;
        *op = make_float2(cur.x + acc.x, cur.y + acc.y);
    } else {
        *reinterpret_cast<float2*>((float*)outv + (long)node * F + lane * 2) = acc;
    }
}

// ----------------------------- MFMA GEMM (layer 1) -------------------------
template<int KP>
__device__ __forceinline__ void gemm_phase(const short* __restrict__ A,
    const short* __restrict__ Whi, const short* __restrict__ Wlo,
    int M, int row0, int col0,
    short (*As)[40], short (*Bh)[40], short (*Bl)[40], f32x4 (&acc)[4][4])
{
    const int tid = threadIdx.x;
    const int lane = tid & 63;
    const int wr = (tid >> 7) & 1, wc = (tid >> 6) & 1;
    const int l15 = lane & 15, l4 = lane >> 4;
    const int sr = tid >> 1;
    const int sk = (tid & 1) * 16;
    const int gr = row0 + sr;

    for (int k0 = 0; k0 < KP; k0 += 32) {
        {
            const short* ap = A + (long)gr * KP + k0 + sk;
            uint4 v0 = make_uint4(0, 0, 0, 0), v1 = make_uint4(0, 0, 0, 0);
            if (gr < M) { v0 = *(const uint4*)ap; v1 = *(const uint4*)(ap + 8); }
            *(uint4*)&As[sr][sk]     = v0;
            *(uint4*)&As[sr][sk + 8] = v1;
        }
        {
            const short* bh = Whi + (long)(col0 + sr) * KP + k0 + sk;
            const short* bl = Wlo + (long)(col0 + sr) * KP + k0 + sk;
            *(uint4*)&Bh[sr][sk]     = *(const uint4*)bh;
            *(uint4*)&Bh[sr][sk + 8] = *(const uint4*)(bh + 8);
            *(uint4*)&Bl[sr][sk]     = *(const uint4*)bl;
            *(uint4*)&Bl[sr][sk + 8] = *(const uint4*)(bl + 8);
        }
        __syncthreads();
        bf16x8 bhf[4], blf[4];
        #pragma unroll
        for (int n = 0; n < 4; ++n) {
            const int br = wc * 64 + n * 16 + l15;
            bhf[n] = *(const bf16x8*)&Bh[br][l4 * 8];
            blf[n] = *(const bf16x8*)&Bl[br][l4 * 8];
        }
        #pragma unroll
        for (int m = 0; m < 4; ++m) {
            const bf16x8 af = *(const bf16x8*)&As[wr * 64 + m * 16 + l15][l4 * 8];
            #pragma unroll
            for (int n = 0; n < 4; ++n) {
                acc[m][n] = __builtin_amdgcn_mfma_f32_16x16x32_bf16(af, bhf[n], acc[m][n], 0, 0, 0);
                acc[m][n] = __builtin_amdgcn_mfma_f32_16x16x32_bf16(af, blf[n], acc[m][n], 0, 0, 0);
            }
        }
        __syncthreads();
    }
}

template<int K1, int K2, int NOUT, bool TWO_PHASE,
         bool RELU, bool HAS_BIAS, bool OUT_BF16>
__global__ __launch_bounds__(256)
void mfma_gemm(const short* __restrict__ A1, const short* __restrict__ A2,
               const short* __restrict__ B1hi, const short* __restrict__ B1lo,
               const short* __restrict__ B2hi, const short* __restrict__ B2lo,
               const float* __restrict__ bias, void* __restrict__ Cv, int M)
{
    __shared__ __align__(16) short As[128][40];
    __shared__ __align__(16) short Bh[128][40];
    __shared__ __align__(16) short Bl[128][40];
    const int row0 = blockIdx.x * 128, col0 = blockIdx.y * 128;
    f32x4 acc[4][4] = {};

    if constexpr (TWO_PHASE)
        gemm_phase<K1>(A1, B1hi, B1lo, M, row0, col0, As, Bh, Bl, acc);
    gemm_phase<K2>(A2, B2hi, B2lo, M, row0, col0, As, Bh, Bl, acc);

    const int tid = threadIdx.x, lane = tid & 63;
    const int wr = (tid >> 7) & 1, wc = (tid >> 6) & 1;
    const int l15 = lane & 15, l4 = lane >> 4;
    float bv[4];
    #pragma unroll
    for (int n = 0; n < 4; ++n)
        bv[n] = HAS_BIAS ? bias[col0 + wc * 64 + n * 16 + l15] : 0.f;
    #pragma unroll
    for (int m = 0; m < 4; ++m) {
        #pragma unroll
        for (int i = 0; i < 4; ++i) {
            const int r = row0 + wr * 64 + m * 16 + l4 * 4 + i;
            if (r < M) {
                #pragma unroll
                for (int n = 0; n < 4; ++n) {
                    const int c = col0 + wc * 64 + n * 16 + l15;
                    float v = acc[m][n][i] + bv[n];
                    if (RELU) v = fmaxf(v, 0.f);
                    if (OUT_BF16) ((short*)Cv)[(long)r * NOUT + c] = (short)f2bf(v);
                    else          ((float*)Cv)[(long)r * NOUT + c] = v;
                }
            }
        }
    }
}

// ----------------------------- dual MFMA GEMM (layer 2) --------------------
template<int K, int NOUT>
__global__ __launch_bounds__(256)
void mfma_gemm_dual(const short* __restrict__ A,
                    const short* __restrict__ Wahi, const short* __restrict__ Walo,
                    const short* __restrict__ Wbhi, const short* __restrict__ Wblo,
                    const float* __restrict__ bias, short* __restrict__ Ca,
                    float* __restrict__ Cb, int M)
{
    __shared__ __align__(16) short As[128][40];
    __shared__ __align__(16) short Bh[2][128][40];
    __shared__ __align__(16) short Bl[2][128][40];
    const int row0 = blockIdx.x * 128;
    f32x4 acc[2][4][4] = {};

    const int tid = threadIdx.x, lane = tid & 63;
    const int wr = (tid >> 7) & 1, wc = (tid >> 6) & 1;
    const int l15 = lane & 15, l4 = lane >> 4;
    const int sr = tid >> 1;
    const int sk = (tid & 1) * 16;
    const int gr = row0 + sr;

    for (int k0 = 0; k0 < K; k0 += 32) {
        {
            const short* ap = A + (long)gr * K + k0 + sk;
            uint4 v0 = make_uint4(0, 0, 0, 0), v1 = make_uint4(0, 0, 0, 0);
            if (gr < M) { v0 = *(const uint4*)ap; v1 = *(const uint4*)(ap + 8); }
            *(uint4*)&As[sr][sk]     = v0;
            *(uint4*)&As[sr][sk + 8] = v1;
        }
        {
            const short* bh0 = Wahi + (long)sr * K + k0 + sk;
            const short* bl0 = Walo + (long)sr * K + k0 + sk;
            const short* bh1 = Wbhi + (long)sr * K + k0 + sk;
            const short* bl1 = Wblo + (long)sr * K + k0 + sk;
            *(uint4*)&Bh[0][sr][sk]     = *(const uint4*)bh0;
            *(uint4*)&Bh[0][sr][sk + 8] = *(const uint4*)(bh0 + 8);
            *(uint4*)&Bl[0][sr][sk]     = *(const uint4*)bl0;
            *(uint4*)&Bl[0][sr][sk + 8] = *(const uint4*)(bl0 + 8);
            *(uint4*)&Bh[1][sr][sk]     = *(const uint4*)bh1;
            *(uint4*)&Bh[1][sr][sk + 8] = *(const uint4*)(bh1 + 8);
            *(uint4*)&Bl[1][sr][sk]     = *(const uint4*)bl1;
            *(uint4*)&Bl[1][sr][sk + 8] = *(const uint4*)(bl1 + 8);
        }
        __syncthreads();
        bf16x8 af[4];
        #pragma unroll
        for (int m = 0; m < 4; ++m)
            af[m] = *(const bf16x8*)&As[wr * 64 + m * 16 + l15][l4 * 8];
        #pragma unroll
        for (int w = 0; w < 2; ++w) {
            #pragma unroll
            for (int n = 0; n < 4; ++n) {
                const int br = wc * 64 + n * 16 + l15;
                const bf16x8 bhf = *(const bf16x8*)&Bh[w][br][l4 * 8];
                const bf16x8 blf = *(const bf16x8*)&Bl[w][br][l4 * 8];
                #pragma unroll
                for (int m = 0; m < 4; ++m) {
                    acc[w][m][n] = __builtin_amdgcn_mfma_f32_16x16x32_bf16(af[m], bhf, acc[w][m][n], 0, 0, 0);
                    acc[w][m][n] = __builtin_amdgcn_mfma_f32_16x16x32_bf16(af[m], blf, acc[w][m][n], 0, 0, 0);
                }
            }
        }
        __syncthreads();
    }

    float bv[4];
    #pragma unroll
    for (int n = 0; n < 4; ++n)
        bv[n] = bias[wc * 64 + n * 16 + l15];
    #pragma unroll
    for (int m = 0; m < 4; ++m) {
        #pragma unroll
        for (int i = 0; i < 4; ++i) {
            const int r = row0 + wr * 64 + m * 16 + l4 * 4 + i;
            if (r < M) {
                #pragma unroll
                for (int n = 0; n < 4; ++n) {
                    const int c = wc * 64 + n * 16 + l15;
                    Ca[(long)r * NOUT + c] = (short)f2bf(acc[0][m][n][i]);
                    Cb[(long)r * NOUT + c] = acc[1][m][n][i] + bv[n];
                }
            }
        }
    }
}

// ----------------------------- launch --------------------------------------
extern "C" void kernel_launch(void* const* d_in, const int* in_sizes, int n_in,
                              void* d_out, int out_size, void* d_ws, size_t ws_size,
                              hipStream_t stream) {
    const float* x   = (const float*)d_in[0];
    const int*   ei  = (const int*)d_in[1];
    const float* W1l = (const float*)d_in[2];
    const float* b1  = (const float*)d_in[3];
    const float* W1r = (const float*)d_in[4];
    const float* W2l = (const float*)d_in[5];
    const float* b2  = (const float*)d_in[6];
    const float* W2r = (const float*)d_in[7];
    float* out = (float*)d_out;

    const int M = in_sizes[0] / 128;   // 50000
    const int E = in_sizes[1] / 2;     // 800000
    const int* src = ei;
    const int* dst = ei + E;

    const int Mal = ((M + 64 + 63) / 64) * 64;
    int* hist       = (int*)d_ws;                               // [Mal] (fallback cursor)
    int* offs       = hist + Mal;                               // [M+1]
    int* bsum       = offs + Mal;                               // [64]
    int* gcur       = bsum + 64;                                // [256]
    uint2* staging  = (uint2*)(gcur + 256);                     // [E] 8B pairs
    int* src_sorted = (int*)(staging + E);                      // [E]
    short* mean1_bf = (short*)(src_sorted + ((E + 63) / 64) * 64); // [M*128] bf16
    short* p_bf     = mean1_bf + (long)M * 128;                 // [M*128] bf16
    short* h_bf     = p_bf + (long)M * 128;                     // [M*256] bf16
    short* wbuf     = h_bf + (long)M * 256;                     // 8 x 32768 shorts
    const int WN = 256 * 128;
    short *W1l_hi = wbuf,          *W1l_lo = wbuf + WN;
    short *W1r_hi = wbuf + 2 * WN, *W1r_lo = wbuf + 3 * WN;
    short *W2l_hi = wbuf + 4 * WN, *W2l_lo = wbuf + 5 * WN;
    short *W2r_hi = wbuf + 6 * WN, *W2r_lo = wbuf + 7 * WN;
    short* x_bf     = wbuf + 8 * WN;                            // [M*128] bf16

    const int TB = 256;
    const int NB   = (M + 2047) / 2048;            // 25 scan blocks
    const int nbF  = (int)((long)M * 128 / 8 / TB);// 3125 f2bf blocks
    const int nbW  = 512;                          // 4 x 128 wsplit blocks
    const int nbH  = (E + 1023) / 1024;            // hist blocks
    const int NMS  = (E + 4095) / 4096;            // msplit blocks
    const int NBK  = (M + 255) / 256;              // buckets

    hipMemsetAsync(hist, 0, (size_t)Mal * sizeof(int), stream);
    prep_kernel<<<dim3(nbF + nbW + nbH), dim3(TB), 0, stream>>>(
        x, x_bf, (long)M * 128, W1l, W1r, W2l, W2r, wbuf, WN, dst, hist, E, nbF, nbW);
    scan_reduce_kernel<<<dim3(NB), dim3(TB), 0, stream>>>(hist, bsum, M);
    scan_root_kernel<<<dim3(1), dim3(64), 0, stream>>>(bsum, NB);
    scan_apply_kernel<<<dim3(NB), dim3(TB), 0, stream>>>(hist, bsum, offs, gcur, M, E);
    msplit_kernel<<<dim3(NMS), dim3(1024), 0, stream>>>(src, dst, gcur, staging, E);
    bsort_kernel<<<dim3(NBK), dim3(1024), 0, stream>>>(staging, offs, hist, src_sorted, M);

    const int MB = (M + 127) / 128;   // 391

    // layer 1
    agg_mean_kernel<128, true, false><<<dim3((M + 3) / 4), dim3(TB), 0, stream>>>(x_bf, src_sorted, offs, mean1_bf, M);
    mfma_gemm<128, 128, 256, true, true, true, true>
        <<<dim3(MB, 2), dim3(TB), 0, stream>>>(mean1_bf, x_bf, W1l_hi, W1l_lo, W1r_hi, W1r_lo,
                                               b1, h_bf, M);
    // layer 2: p = h@W2l^T (bf16), out = h@W2r^T + b2 (fp32), h staged once
    mfma_gemm_dual<256, 128>
        <<<dim3(MB), dim3(TB), 0, stream>>>(h_bf, W2l_hi, W2l_lo, W2r_hi, W2r_lo,
                                            b2, p_bf, out, M);
    // out += mean_agg(p)
    agg_mean_kernel<128, false, true><<<dim3((M + 3) / 4), dim3(TB), 0, stream>>>(p_bf, src_sorted, offs, out, M);
}

// Round 9
// 243.523 us; speedup vs baseline: 12.3827x; 1.1435x over previous
//
#include <hip/hip_runtime.h>

// ---------------------------------------------------------------------------
// 2-layer GraphSAGE (mean aggr), CSR-pull aggregation + bf16-MFMA GEMMs.
//   prep: x->bf16 + weight hi/lo split + COARSE (dst>>8) LDS histogram
//   ccscan: 1-block scan of 196 coarse counts -> cbase/gcur
//   msplit: block-local LDS sort by dst>>8, coalesced run flush -> staging
//   bsort: per-bucket fine hist -> offs[] + counting sort -> src_sorted
//   mean1 = mean_agg(x_bf)                      -> bf16   [M,128]
//   h     = relu(mean1@W1l^T + b1 + x_bf@W1r^T) -> bf16   [M,256]  (MFMA)
//   {p, out0} = h @ {W2l,W2r}^T (dual GEMM)  p->bf16, out0=h@W2r^T+b2 (fp32)
//   out  += mean_agg(p)
// ws: ccount|cbase|gcur|offs | staging(uint2 E) | src_sorted[E]
//     | mean1_bf | p_bf | h_bf | wbuf | x_bf    total ~74MB
// ---------------------------------------------------------------------------

typedef short bf16x8 __attribute__((ext_vector_type(8)));
typedef float f32x4  __attribute__((ext_vector_type(4)));

__device__ __forceinline__ unsigned f2bf(float f) {         // RNE fp32->bf16 bits
    unsigned u = __float_as_uint(f);
    return (u + 0x7FFFu + ((u >> 16) & 1u)) >> 16;
}
__device__ __forceinline__ unsigned pack2(float a, float b) {
    return f2bf(a) | (f2bf(b) << 16);
}
__device__ __forceinline__ float2 bfunpack(unsigned u) {    // (low, high) bf16 -> fp32
    return make_float2(__uint_as_float(u << 16), __uint_as_float(u & 0xffff0000u));
}

// exclusive scan of 256 ints in LDS (wave 0 only; caller syncs)
__device__ __forceinline__ void scan256(const int* __restrict__ h,
                                        int* __restrict__ out, int tid) {
    if (tid < 64) {
        const int i4 = tid * 4;
        const int v0 = h[i4], v1 = h[i4 + 1], v2 = h[i4 + 2], v3 = h[i4 + 3];
        const int t = v0 + v1 + v2 + v3;
        int x = t;
        #pragma unroll
        for (int dd = 1; dd < 64; dd <<= 1) {
            const int y = __shfl_up(x, dd, 64);
            if (tid >= dd) x += y;
        }
        const int ex = x - t;
        out[i4] = ex; out[i4 + 1] = ex + v0;
        out[i4 + 2] = ex + v0 + v1; out[i4 + 3] = ex + v0 + v1 + v2;
    }
}

// ----------------------------- fused prep ----------------------------------
// roles by blockIdx.x: [0,nbF) f2bf | [nbF,nbF+nbW) wsplit | rest: coarse count
__global__ __launch_bounds__(256)
void prep_kernel(const float* __restrict__ x, short* __restrict__ x_bf, long nx,
                 const float* __restrict__ W0, const float* __restrict__ W1,
                 const float* __restrict__ W2, const float* __restrict__ W3,
                 short* __restrict__ wbuf, int wn,
                 const int* __restrict__ dst, int* __restrict__ ccount, int E,
                 int nbF, int nbW) {
    __shared__ int ch[256];
    const int bx = blockIdx.x, tid = threadIdx.x;
    if (bx < nbF) {
        const long i = ((long)bx * 256 + tid) * 8;
        if (i + 8 <= nx) {
            const float4 a = *(const float4*)(x + i);
            const float4 b = *(const float4*)(x + i + 4);
            *(uint4*)(x_bf + i) = make_uint4(pack2(a.x, a.y), pack2(a.z, a.w),
                                             pack2(b.x, b.y), pack2(b.z, b.w));
        }
    } else if (bx < nbF + nbW) {
        const int rel = bx - nbF;
        const int w = rel >> 7;                  // 128 blocks per weight
        const float* __restrict__ W = (w == 0) ? W0 : (w == 1) ? W1 : (w == 2) ? W2 : W3;
        short* hi = wbuf + (long)(2 * w) * wn;
        short* lo = hi + wn;
        const int i = (rel & 127) * 256 + tid;
        if (i < wn) {
            const float v = W[i];
            const unsigned h = f2bf(v);
            hi[i] = (short)h;
            lo[i] = (short)f2bf(v - __uint_as_float(h << 16));
        }
    } else {
        const int hb = bx - nbF - nbW;
        ch[tid] = 0;
        __syncthreads();
        const long base = (long)hb * 8192;
        #pragma unroll
        for (int k = 0; k < 32; ++k) {
            const long i = base + (long)k * 256 + tid;
            if (i < E) atomicAdd(&ch[dst[i] >> 8], 1);
        }
        __syncthreads();
        const int c = ch[tid];
        if (c) atomicAdd(&ccount[tid], c);
    }
}

// ----------------------------- coarse scan (1 block, 64 thr) ---------------
__global__ void ccscan_kernel(const int* __restrict__ ccount, int* __restrict__ cbase,
                              int* __restrict__ gcur, int NBK, int E) {
    const int lane = threadIdx.x;   // 64 threads
    int v[4]; int t = 0;
    #pragma unroll
    for (int i = 0; i < 4; ++i) {
        const int b = lane * 4 + i;
        v[i] = (b < NBK) ? ccount[b] : 0;
        t += v[i];
    }
    int x = t;
    #pragma unroll
    for (int d = 1; d < 64; d <<= 1) {
        const int y = __shfl_up(x, d, 64);
        if (lane >= d) x += y;
    }
    int ex = x - t;   // exclusive prefix of this thread's chunk
    #pragma unroll
    for (int i = 0; i < 4; ++i) {
        const int b = lane * 4 + i;
        if (b < NBK) { cbase[b] = ex; gcur[b] = ex; }
        ex += v[i];
    }
    if (lane == 63) cbase[NBK] = E;
}

// ----------------------------- coarse multisplit ---------------------------
// 4096 edges/block; LDS counting sort by dst>>8; coalesced run flush.
__global__ __launch_bounds__(1024)
void msplit_kernel(const int* __restrict__ src, const int* __restrict__ dst,
                   int* __restrict__ gcur, uint2* __restrict__ staging, int E) {
    __shared__ int hist[256], scanex[256], gb[256];
    __shared__ uint2 pairs[4096];
    const int tid = threadIdx.x;
    const long base = (long)blockIdx.x * 4096;
    const int cnt = min(4096, (int)(E - base));
    if (tid < 256) hist[tid] = 0;
    __syncthreads();
    int d[4], s[4];
    #pragma unroll
    for (int k = 0; k < 4; ++k) {
        const int i = tid + k * 1024;
        if (i < cnt) {
            d[k] = dst[base + i]; s[k] = src[base + i];
            atomicAdd(&hist[d[k] >> 8], 1);
        }
    }
    __syncthreads();
    scan256(hist, scanex, tid);
    __syncthreads();
    if (tid < 256) {
        const int c = hist[tid];
        gb[tid] = c ? atomicAdd(&gcur[tid], c) : 0;
        hist[tid] = scanex[tid];                 // becomes LDS cursor
    }
    __syncthreads();
    #pragma unroll
    for (int k = 0; k < 4; ++k) {
        const int i = tid + k * 1024;
        if (i < cnt) {
            const int b = d[k] >> 8;
            const int pos = atomicAdd(&hist[b], 1);
            pairs[pos] = make_uint2((unsigned)s[k], (unsigned)d[k]);
        }
    }
    __syncthreads();
    #pragma unroll
    for (int k = 0; k < 4; ++k) {
        const int i = tid + k * 1024;
        if (i < cnt) {
            const uint2 pr = pairs[i];
            const int b = (int)(pr.y >> 8);
            staging[gb[b] + (i - scanex[b])] = pr;    // bucket-contiguous runs
        }
    }
}

// ----------------------------- per-bucket sort + offs ----------------------
// one block per 256-node bucket; fine hist -> offs; counting sort -> src_sorted.
__global__ __launch_bounds__(1024)
void bsort_kernel(const uint2* __restrict__ staging, const int* __restrict__ cbase,
                  int* __restrict__ offs, int* __restrict__ src_sorted,
                  int M, int NBK) {
    const int b = blockIdx.x;
    const int n0 = b * 256;
    const int s0 = cbase[b], s1 = cbase[b + 1];
    const int cnt = s1 - s0;
    const int tid = threadIdx.x;
    __shared__ int hist[256], base2[256];
    __shared__ int lsrc[8192];
    if (tid < 256) hist[tid] = 0;
    __syncthreads();
    for (int i = tid; i < cnt; i += 1024)
        atomicAdd(&hist[staging[s0 + i].y & 255], 1);
    __syncthreads();
    scan256(hist, base2, tid);
    __syncthreads();
    if (tid < 256) {
        const int node = n0 + tid;
        if (node < M) offs[node] = s0 + base2[tid];
        hist[tid] = base2[tid];                  // becomes cursor
    }
    if (b == NBK - 1 && tid == 0) offs[M] = s1;
    __syncthreads();
    if (cnt <= 8192) {
        for (int i = tid; i < cnt; i += 1024) {
            const uint2 pr = staging[s0 + i];
            const int pos = atomicAdd(&hist[pr.y & 255], 1);
            lsrc[pos] = (int)pr.x;
        }
        __syncthreads();
        for (int i = tid; i < cnt; i += 1024)
            src_sorted[s0 + i] = lsrc[i];        // fully coalesced
    } else {                                     // rare huge-bucket fallback
        for (int i = tid; i < cnt; i += 1024) {
            const uint2 pr = staging[s0 + i];
            const int pos = atomicAdd(&hist[pr.y & 255], 1);
            src_sorted[s0 + pos] = (int)pr.x;
        }
    }
}

// ----------------------------- aggregation ---------------------------------
template<int F, bool BF16_OUT, bool ADD>
__global__ __launch_bounds__(256)
void agg_mean_kernel(const short* __restrict__ feat, const int* __restrict__ src_sorted,
                     const int* __restrict__ offs, void* __restrict__ outv, int M) {
    const int node = blockIdx.x * 4 + (threadIdx.x >> 6);
    if (node >= M) return;
    const int lane = threadIdx.x & 63;
    const int start = offs[node], end = offs[node + 1];
    const unsigned* fb = (const unsigned*)feat;       // row stride F/2 dwords
    float2 acc = make_float2(0.f, 0.f);
    for (int e0 = start; e0 < end; e0 += 64) {
        const int n = min(64, end - e0);
        const int sv = (e0 + lane < end) ? src_sorted[e0 + lane] : 0;
        int j = 0;
        for (; j + 4 <= n; j += 4) {
            const int s0 = __shfl(sv, j, 64),     s1 = __shfl(sv, j + 1, 64);
            const int s2 = __shfl(sv, j + 2, 64), s3 = __shfl(sv, j + 3, 64);
            const unsigned u0 = fb[(long)s0 * (F / 2) + lane];
            const unsigned u1 = fb[(long)s1 * (F / 2) + lane];
            const unsigned u2 = fb[(long)s2 * (F / 2) + lane];
            const unsigned u3 = fb[(long)s3 * (F / 2) + lane];
            const float2 v0 = bfunpack(u0), v1 = bfunpack(u1);
            const float2 v2 = bfunpack(u2), v3 = bfunpack(u3);
            acc.x += (v0.x + v1.x) + (v2.x + v3.x);
            acc.y += (v0.y + v1.y) + (v2.y + v3.y);
        }
        for (; j < n; ++j) {
            const int s = __shfl(sv, j, 64);
            const float2 v = bfunpack(fb[(long)s * (F / 2) + lane]);
            acc.x += v.x; acc.y += v.y;
        }
    }
    const float inv = (end > start) ? 1.0f / (float)(end - start) : 0.f;
    acc.x *= inv; acc.y *= inv;
    if (BF16_OUT) {
        ((unsigned*)outv)[(long)node * (F / 2) + lane] = pack2(acc.x, acc.y);
    } else if (ADD) {
        float2* op = reinterpret_cast<float2*>((float*)outv + (long)node * F + lane * 2);
        const float2 cur = *op;
        *op = make_float2(cur.x + acc.x, cur.y + acc.y);
    } else {
        *reinterpret_cast<float2*>((float*)outv + (long)node * F + lane * 2) = acc;
    }
}

// ----------------------------- MFMA GEMM (layer 1) -------------------------
template<int KP>
__device__ __forceinline__ void gemm_phase(const short* __restrict__ A,
    const short* __restrict__ Whi, const short* __restrict__ Wlo,
    int M, int row0, int col0,
    short (*As)[40], short (*Bh)[40], short (*Bl)[40], f32x4 (&acc)[4][4])
{
    const int tid = threadIdx.x;
    const int lane = tid & 63;
    const int wr = (tid >> 7) & 1, wc = (tid >> 6) & 1;
    const int l15 = lane & 15, l4 = lane >> 4;
    const int sr = tid >> 1;
    const int sk = (tid & 1) * 16;
    const int gr = row0 + sr;

    for (int k0 = 0; k0 < KP; k0 += 32) {
        {
            const short* ap = A + (long)gr * KP + k0 + sk;
            uint4 v0 = make_uint4(0, 0, 0, 0), v1 = make_uint4(0, 0, 0, 0);
            if (gr < M) { v0 = *(const uint4*)ap; v1 = *(const uint4*)(ap + 8); }
            *(uint4*)&As[sr][sk]     = v0;
            *(uint4*)&As[sr][sk + 8] = v1;
        }
        {
            const short* bh = Whi + (long)(col0 + sr) * KP + k0 + sk;
            const short* bl = Wlo + (long)(col0 + sr) * KP + k0 + sk;
            *(uint4*)&Bh[sr][sk]     = *(const uint4*)bh;
            *(uint4*)&Bh[sr][sk + 8] = *(const uint4*)(bh + 8);
            *(uint4*)&Bl[sr][sk]     = *(const uint4*)bl;
            *(uint4*)&Bl[sr][sk + 8] = *(const uint4*)(bl + 8);
        }
        __syncthreads();
        bf16x8 bhf[4], blf[4];
        #pragma unroll
        for (int n = 0; n < 4; ++n) {
            const int br = wc * 64 + n * 16 + l15;
            bhf[n] = *(const bf16x8*)&Bh[br][l4 * 8];
            blf[n] = *(const bf16x8*)&Bl[br][l4 * 8];
        }
        #pragma unroll
        for (int m = 0; m < 4; ++m) {
            const bf16x8 af = *(const bf16x8*)&As[wr * 64 + m * 16 + l15][l4 * 8];
            #pragma unroll
            for (int n = 0; n < 4; ++n) {
                acc[m][n] = __builtin_amdgcn_mfma_f32_16x16x32_bf16(af, bhf[n], acc[m][n], 0, 0, 0);
                acc[m][n] = __builtin_amdgcn_mfma_f32_16x16x32_bf16(af, blf[n], acc[m][n], 0, 0, 0);
            }
        }
        __syncthreads();
    }
}

template<int K1, int K2, int NOUT, bool TWO_PHASE,
         bool RELU, bool HAS_BIAS, bool OUT_BF16>
__global__ __launch_bounds__(256)
void mfma_gemm(const short* __restrict__ A1, const short* __restrict__ A2,
               const short* __restrict__ B1hi, const short* __restrict__ B1lo,
               const short* __restrict__ B2hi, const short* __restrict__ B2lo,
               const float* __restrict__ bias, void* __restrict__ Cv, int M)
{
    __shared__ __align__(16) short As[128][40];
    __shared__ __align__(16) short Bh[128][40];
    __shared__ __align__(16) short Bl[128][40];
    const int row0 = blockIdx.x * 128, col0 = blockIdx.y * 128;
    f32x4 acc[4][4] = {};

    if constexpr (TWO_PHASE)
        gemm_phase<K1>(A1, B1hi, B1lo, M, row0, col0, As, Bh, Bl, acc);
    gemm_phase<K2>(A2, B2hi, B2lo, M, row0, col0, As, Bh, Bl, acc);

    const int tid = threadIdx.x, lane = tid & 63;
    const int wr = (tid >> 7) & 1, wc = (tid >> 6) & 1;
    const int l15 = lane & 15, l4 = lane >> 4;
    float bv[4];
    #pragma unroll
    for (int n = 0; n < 4; ++n)
        bv[n] = HAS_BIAS ? bias[col0 + wc * 64 + n * 16 + l15] : 0.f;
    #pragma unroll
    for (int m = 0; m < 4; ++m) {
        #pragma unroll
        for (int i = 0; i < 4; ++i) {
            const int r = row0 + wr * 64 + m * 16 + l4 * 4 + i;
            if (r < M) {
                #pragma unroll
                for (int n = 0; n < 4; ++n) {
                    const int c = col0 + wc * 64 + n * 16 + l15;
                    float v = acc[m][n][i] + bv[n];
                    if (RELU) v = fmaxf(v, 0.f);
                    if (OUT_BF16) ((short*)Cv)[(long)r * NOUT + c] = (short)f2bf(v);
                    else          ((float*)Cv)[(long)r * NOUT + c] = v;
                }
            }
        }
    }
}

// ----------------------------- dual MFMA GEMM (layer 2) --------------------
template<int K, int NOUT>
__global__ __launch_bounds__(256)
void mfma_gemm_dual(const short* __restrict__ A,
                    const short* __restrict__ Wahi, const short* __restrict__ Walo,
                    const short* __restrict__ Wbhi, const short* __restrict__ Wblo,
                    const float* __restrict__ bias, short* __restrict__ Ca,
                    float* __restrict__ Cb, int M)
{
    __shared__ __align__(16) short As[128][40];
    __shared__ __align__(16) short Bh[2][128][40];
    __shared__ __align__(16) short Bl[2][128][40];
    const int row0 = blockIdx.x * 128;
    f32x4 acc[2][4][4] = {};

    const int tid = threadIdx.x, lane = tid & 63;
    const int wr = (tid >> 7) & 1, wc = (tid >> 6) & 1;
    const int l15 = lane & 15, l4 = lane >> 4;
    const int sr = tid >> 1;
    const int sk = (tid & 1) * 16;
    const int gr = row0 + sr;

    for (int k0 = 0; k0 < K; k0 += 32) {
        {
            const short* ap = A + (long)gr * K + k0 + sk;
            uint4 v0 = make_uint4(0, 0, 0, 0), v1 = make_uint4(0, 0, 0, 0);
            if (gr < M) { v0 = *(const uint4*)ap; v1 = *(const uint4*)(ap + 8); }
            *(uint4*)&As[sr][sk]     = v0;
            *(uint4*)&As[sr][sk + 8] = v1;
        }
        {
            const short* bh0 = Wahi + (long)sr * K + k0 + sk;
            const short* bl0 = Walo + (long)sr * K + k0 + sk;
            const short* bh1 = Wbhi + (long)sr * K + k0 + sk;
            const short* bl1 = Wblo + (long)sr * K + k0 + sk;
            *(uint4*)&Bh[0][sr][sk]     = *(const uint4*)bh0;
            *(uint4*)&Bh[0][sr][sk + 8] = *(const uint4*)(bh0 + 8);
            *(uint4*)&Bl[0][sr][sk]     = *(const uint4*)bl0;
            *(uint4*)&Bl[0][sr][sk + 8] = *(const uint4*)(bl0 + 8);
            *(uint4*)&Bh[1][sr][sk]     = *(const uint4*)bh1;
            *(uint4*)&Bh[1][sr][sk + 8] = *(const uint4*)(bh1 + 8);
            *(uint4*)&Bl[1][sr][sk]     = *(const uint4*)bl1;
            *(uint4*)&Bl[1][sr][sk + 8] = *(const uint4*)(bl1 + 8);
        }
        __syncthreads();
        bf16x8 af[4];
        #pragma unroll
        for (int m = 0; m < 4; ++m)
            af[m] = *(const bf16x8*)&As[wr * 64 + m * 16 + l15][l4 * 8];
        #pragma unroll
        for (int w = 0; w < 2; ++w) {
            #pragma unroll
            for (int n = 0; n < 4; ++n) {
                const int br = wc * 64 + n * 16 + l15;
                const bf16x8 bhf = *(const bf16x8*)&Bh[w][br][l4 * 8];
                const bf16x8 blf = *(const bf16x8*)&Bl[w][br][l4 * 8];
                #pragma unroll
                for (int m = 0; m < 4; ++m) {
                    acc[w][m][n] = __builtin_amdgcn_mfma_f32_16x16x32_bf16(af[m], bhf, acc[w][m][n], 0, 0, 0);
                    acc[w][m][n] = __builtin_amdgcn_mfma_f32_16x16x32_bf16(af[m], blf, acc[w][m][n], 0, 0, 0);
                }
            }
        }
        __syncthreads();
    }

    float bv[4];
    #pragma unroll
    for (int n = 0; n < 4; ++n)
        bv[n] = bias[wc * 64 + n * 16 + l15];
    #pragma unroll
    for (int m = 0; m < 4; ++m) {
        #pragma unroll
        for (int i = 0; i < 4; ++i) {
            const int r = row0 + wr * 64 + m * 16 + l4 * 4 + i;
            if (r < M) {
                #pragma unroll
                for (int n = 0; n < 4; ++n) {
                    const int c = wc * 64 + n * 16 + l15;
                    Ca[(long)r * NOUT + c] = (short)f2bf(acc[0][m][n][i]);
                    Cb[(long)r * NOUT + c] = acc[1][m][n][i] + bv[n];
                }
            }
        }
    }
}

// ----------------------------- launch --------------------------------------
extern "C" void kernel_launch(void* const* d_in, const int* in_sizes, int n_in,
                              void* d_out, int out_size, void* d_ws, size_t ws_size,
                              hipStream_t stream) {
    const float* x   = (const float*)d_in[0];
    const int*   ei  = (const int*)d_in[1];
    const float* W1l = (const float*)d_in[2];
    const float* b1  = (const float*)d_in[3];
    const float* W1r = (const float*)d_in[4];
    const float* W2l = (const float*)d_in[5];
    const float* b2  = (const float*)d_in[6];
    const float* W2r = (const float*)d_in[7];
    float* out = (float*)d_out;

    const int M = in_sizes[0] / 128;   // 50000
    const int E = in_sizes[1] / 2;     // 800000
    const int* src = ei;
    const int* dst = ei + E;

    const int NBK = (M + 255) / 256;               // 196 coarse buckets
    const int Mal = ((M + 1 + 63) / 64) * 64;

    int* ccount     = (int*)d_ws;                               // [256]
    int* cbase      = ccount + 256;                             // [NBK+1] (<=320)
    int* gcur       = cbase + 320;                              // [256]
    int* offs       = gcur + 256;                               // [M+1]
    uint2* staging  = (uint2*)(offs + Mal);                     // [E] 8B pairs
    int* src_sorted = (int*)(staging + E);                      // [E]
    short* mean1_bf = (short*)(src_sorted + ((E + 63) / 64) * 64); // [M*128] bf16
    short* p_bf     = mean1_bf + (long)M * 128;                 // [M*128] bf16
    short* h_bf     = p_bf + (long)M * 128;                     // [M*256] bf16
    short* wbuf     = h_bf + (long)M * 256;                     // 8 x 32768 shorts
    const int WN = 256 * 128;
    short *W1l_hi = wbuf,          *W1l_lo = wbuf + WN;
    short *W1r_hi = wbuf + 2 * WN, *W1r_lo = wbuf + 3 * WN;
    short *W2l_hi = wbuf + 4 * WN, *W2l_lo = wbuf + 5 * WN;
    short *W2r_hi = wbuf + 6 * WN, *W2r_lo = wbuf + 7 * WN;
    short* x_bf     = wbuf + 8 * WN;                            // [M*128] bf16

    const int TB = 256;
    const int nbF  = (int)(((long)M * 128 / 8 + TB - 1) / TB); // f2bf blocks
    const int nbW  = 512;                          // 4 x 128 wsplit blocks
    const int nbC  = (E + 8191) / 8192;            // coarse-count blocks
    const int NMS  = (E + 4095) / 4096;            // msplit blocks

    hipMemsetAsync(ccount, 0, 256 * sizeof(int), stream);
    prep_kernel<<<dim3(nbF + nbW + nbC), dim3(TB), 0, stream>>>(
        x, x_bf, (long)M * 128, W1l, W1r, W2l, W2r, wbuf, WN, dst, ccount, E, nbF, nbW);
    ccscan_kernel<<<dim3(1), dim3(64), 0, stream>>>(ccount, cbase, gcur, NBK, E);
    msplit_kernel<<<dim3(NMS), dim3(1024), 0, stream>>>(src, dst, gcur, staging, E);
    bsort_kernel<<<dim3(NBK), dim3(1024), 0, stream>>>(staging, cbase, offs, src_sorted, M, NBK);

    const int MB = (M + 127) / 128;   // 391

    // layer 1
    agg_mean_kernel<128, true, false><<<dim3((M + 3) / 4), dim3(TB), 0, stream>>>(x_bf, src_sorted, offs, mean1_bf, M);
    mfma_gemm<128, 128, 256, true, true, true, true>
        <<<dim3(MB, 2), dim3(TB), 0, stream>>>(mean1_bf, x_bf, W1l_hi, W1l_lo, W1r_hi, W1r_lo,
                                               b1, h_bf, M);
    // layer 2: p = h@W2l^T (bf16), out = h@W2r^T + b2 (fp32), h staged once
    mfma_gemm_dual<256, 128>
        <<<dim3(MB), dim3(TB), 0, stream>>>(h_bf, W2l_hi, W2l_lo, W2r_hi, W2r_lo,
                                            b2, p_bf, out, M);
    // out += mean_agg(p)
    agg_mean_kernel<128, false, true><<<dim3((M + 3) / 4), dim3(TB), 0, stream>>>(p_bf, src_sorted, offs, out, M);
}